// Round 6
// baseline (2716.799 us; speedup 1.0000x reference)
//
#include <hip/hip_runtime.h>
#include <hip/hip_bf16.h>

#define NN 50000
#define NE 500000
#define HD 128

typedef __attribute__((ext_vector_type(4))) float floatx4;

// ---------------- zero the f32 accumulator ----------------
__global__ __launch_bounds__(256) void k_zero(float* __restrict__ p) {
    int i = blockIdx.x * 256 + threadIdx.x;
    floatx4 z = {0.f, 0.f, 0.f, 0.f};
    ((floatx4*)p)[i] = z;
}

// ---------------- scatter-add: aggr[dst] += x[src], all f32 ----------------
// 32 threads per edge, 4 features per thread. HW f32 atomics (verified accumulating
// on d_ws via R2-vs-R3 agreement).
__global__ __launch_bounds__(256) void k_scatter(const float* __restrict__ x,
                                                 const int* __restrict__ edge,
                                                 float* __restrict__ aggr) {
    int tid = blockIdx.x * 256 + threadIdx.x;
    int e = tid >> 5;
    int c = (tid & 31) << 2;
    int dst = edge[e];        // edge_ba[0][e]  (segment id)
    int src = edge[NE + e];   // edge_ba[1][e]  (gather index)
    const floatx4 v = *(const floatx4*)(x + src * HD + c);
    float* ap = aggr + dst * HD + c;
    unsafeAtomicAdd(ap + 0, v[0]);
    unsafeAtomicAdd(ap + 1, v[1]);
    unsafeAtomicAdd(ap + 2, v[2]);
    unsafeAtomicAdd(ap + 3, v[3]);
}

// ---------------- GEMM1 (VALU f32): h = relu(aggr@wl^T + x@(w0+w1)^T + bias) ----------------
// Block = 256 thr = 2 rows x 128 cols. A-rows staged in LDS (broadcast reads).
// Weight rows read from global (64 KB each, L1/L2-resident).
__global__ __launch_bounds__(256) void k_gemm1(
    const float* __restrict__ aggr, const float* __restrict__ x,
    const float* __restrict__ wl, const float* __restrict__ w0, const float* __restrict__ w1,
    const float* __restrict__ bl, const float* __restrict__ b0, const float* __restrict__ b1,
    float* __restrict__ hout)
{
    __shared__ alignas(16) float ag_s[2][128];
    __shared__ alignas(16) float x_s[2][128];
    const int tid = threadIdx.x;
    const int r = tid >> 7;        // local row 0/1
    const int n = tid & 127;       // output column
    const int m = blockIdx.x * 2 + r;

    ag_s[r][n] = aggr[m * HD + n];
    x_s[r][n]  = x[m * HD + n];
    __syncthreads();

    const floatx4* wl4 = (const floatx4*)(wl + n * HD);
    const floatx4* w04 = (const floatx4*)(w0 + n * HD);
    const floatx4* w14 = (const floatx4*)(w1 + n * HD);
    const floatx4* ag4 = (const floatx4*)(ag_s[r]);
    const floatx4* xx4 = (const floatx4*)(x_s[r]);

    float acc = bl[n] + b0[n] + b1[n];
#pragma unroll
    for (int k4 = 0; k4 < HD / 4; k4++) {
        const floatx4 a  = ag4[k4];
        const floatx4 xv = xx4[k4];
        const floatx4 lw = wl4[k4];
        const floatx4 u0 = w04[k4];
        const floatx4 u1 = w14[k4];
#pragma unroll
        for (int j = 0; j < 4; j++)
            acc += a[j] * lw[j] + xv[j] * (u0[j] + u1[j]);
    }
    hout[m * HD + n] = (acc > 0.f ? acc : 0.f);
}

// ---------------- GEMM2 (VALU f32): out = h @ out_w^T + out_b, in-place over d_out ----------------
// Block stages its own 2 rows of h into LDS before any write -> in-place safe.
__global__ __launch_bounds__(256) void k_gemm2(
    const float* __restrict__ h, const float* __restrict__ ow, const float* __restrict__ ob,
    float* __restrict__ out)
{
    __shared__ alignas(16) float h_s[2][128];
    const int tid = threadIdx.x;
    const int r = tid >> 7;
    const int n = tid & 127;
    const int m = blockIdx.x * 2 + r;

    h_s[r][n] = h[m * HD + n];
    __syncthreads();

    const floatx4* ow4 = (const floatx4*)(ow + n * HD);
    const floatx4* hh4 = (const floatx4*)(h_s[r]);

    float acc = ob[n];
#pragma unroll
    for (int k4 = 0; k4 < HD / 4; k4++) {
        const floatx4 hv = hh4[k4];
        const floatx4 wv = ow4[k4];
#pragma unroll
        for (int j = 0; j < 4; j++)
            acc += hv[j] * wv[j];
    }
    out[m * HD + n] = acc;
}

extern "C" void kernel_launch(void* const* d_in, const int* in_sizes, int n_in,
                              void* d_out, int out_size, void* d_ws, size_t ws_size,
                              hipStream_t stream) {
    // Dtype resolution (R4+R5 evidence): inputs f32, indices int32, OUTPUT f32.
    // The "(bf16, ...)" in the harness assertion label is literal f-string text
    // (bf16-floored threshold mode), not the output dtype.
    // Live inputs only (h_b / conv0 / x_b / edge_ab are dead code in the reference).
    const float* x_a     = (const float*)d_in[0];
    const int*   edge_ba = (const int*)d_in[3];
    const float* c1_w0_w = (const float*)d_in[10];
    const float* c1_w0_b = (const float*)d_in[11];
    const float* c1_wl_w = (const float*)d_in[12];
    const float* c1_wl_b = (const float*)d_in[13];
    const float* c1_w1_w = (const float*)d_in[14];
    const float* c1_w1_b = (const float*)d_in[15];
    const float* out_w   = (const float*)d_in[16];
    const float* out_b   = (const float*)d_in[17];

    float* aggr = (float*)d_ws;     // N*H f32 (25.6 MB) — only ws use (proven safe)
    float* hbuf = (float*)d_out;    // h_a (f32) lives in d_out; GEMM2 row-local in-place

    k_zero   <<<NN * HD / 4 / 256, 256, 0, stream>>>(aggr);               // 6250 blocks
    k_scatter<<<NE * 32 / 256,     256, 0, stream>>>(x_a, edge_ba, aggr); // 62500 blocks
    k_gemm1  <<<NN / 2,            256, 0, stream>>>(aggr, x_a, c1_wl_w, c1_w0_w, c1_w1_w,
                                                     c1_wl_b, c1_w0_b, c1_w1_b, hbuf);
    k_gemm2  <<<NN / 2,            256, 0, stream>>>(hbuf, out_w, out_b, (float*)d_out);
}

// Round 7
// 992.020 us; speedup vs baseline: 2.7387x; 2.7387x over previous
//
#include <hip/hip_runtime.h>
#include <hip/hip_bf16.h>

#define NN 50000
#define NE 500000
#define HD 128

typedef __bf16 bf16;
typedef __attribute__((ext_vector_type(8))) __bf16 bf16x8;
typedef __attribute__((ext_vector_type(4))) float floatx4;

__device__ inline bf16x8 cvt8(floatx4 a, floatx4 b) {
    bf16x8 r;
#pragma unroll
    for (int j = 0; j < 4; j++) { r[j] = (bf16)a[j]; r[j + 4] = (bf16)b[j]; }
    return r;
}

// split f32x8 into bf16 hi + bf16 lo (residual) for compensated MFMA
__device__ inline void split8(const floatx4 f0, const floatx4 f1, bf16x8& hi, bf16x8& lo) {
#pragma unroll
    for (int j = 0; j < 4; j++) {
        float a = f0[j]; bf16 h = (bf16)a; hi[j] = h; lo[j] = (bf16)(a - (float)h);
        float b = f1[j]; bf16 g = (bf16)b; hi[j + 4] = g; lo[j + 4] = (bf16)(b - (float)g);
    }
}

__device__ inline bf16x8 zero8() {
    bf16x8 v;
#pragma unroll
    for (int j = 0; j < 8; j++) v[j] = (bf16)0.f;
    return v;
}

// ---------------- zero the f32 accumulator ----------------
__global__ __launch_bounds__(256) void k_zero(float* __restrict__ p) {
    int i = blockIdx.x * 256 + threadIdx.x;
    floatx4 z = {0.f, 0.f, 0.f, 0.f};
    ((floatx4*)p)[i] = z;
}

// ---------------- scatter-add: aggr[dst] += x[src], all f32 ----------------
__global__ __launch_bounds__(256) void k_scatter(const float* __restrict__ x,
                                                 const int* __restrict__ edge,
                                                 float* __restrict__ aggr) {
    int tid = blockIdx.x * 256 + threadIdx.x;
    int e = tid >> 5;
    int c = (tid & 31) << 2;
    int dst = edge[e];        // edge_ba[0][e]
    int src = edge[NE + e];   // edge_ba[1][e]
    const floatx4 v = *(const floatx4*)(x + src * HD + c);
    float* ap = aggr + dst * HD + c;
    unsafeAtomicAdd(ap + 0, v[0]);
    unsafeAtomicAdd(ap + 1, v[1]);
    unsafeAtomicAdd(ap + 2, v[2]);
    unsafeAtomicAdd(ap + 3, v[3]);
}

// ---------------- GEMM1 (MFMA): h = relu(aggr@wl^T + x@(w0+w1)^T + bias) ----------------
// 4 waves/block, 16 rows/wave. aggr compensated hi+lo. Weights bf16 in LDS (stride 136).
__global__ __launch_bounds__(256) void k_gemm1(
    const float* __restrict__ aggr, const float* __restrict__ x,
    const float* __restrict__ wl, const float* __restrict__ w0, const float* __restrict__ w1,
    const float* __restrict__ bl, const float* __restrict__ b0, const float* __restrict__ b1,
    float* __restrict__ hout)
{
    __shared__ bf16 wl_s[128 * 136];
    __shared__ bf16 w01_s[128 * 136];
    __shared__ float bias_s[128];
    const int tid = threadIdx.x;

#pragma unroll
    for (int it = 0; it < 8; it++) {
        int i = tid + it * 256;          // 2048 chunks of 8 elements
        int r = i >> 4;
        int o = (i & 15) << 3;
        const floatx4 l0 = *(const floatx4*)(wl + r * 128 + o);
        const floatx4 l1 = *(const floatx4*)(wl + r * 128 + o + 4);
        *(bf16x8*)(wl_s + r * 136 + o) = cvt8(l0, l1);
        floatx4 s0 = *(const floatx4*)(w0 + r * 128 + o);
        floatx4 s1 = *(const floatx4*)(w0 + r * 128 + o + 4);
        const floatx4 t0 = *(const floatx4*)(w1 + r * 128 + o);
        const floatx4 t1 = *(const floatx4*)(w1 + r * 128 + o + 4);
#pragma unroll
        for (int j = 0; j < 4; j++) { s0[j] += t0[j]; s1[j] += t1[j]; }
        *(bf16x8*)(w01_s + r * 136 + o) = cvt8(s0, s1);
    }
    if (tid < 128) bias_s[tid] = bl[tid] + b0[tid] + b1[tid];
    __syncthreads();

    const int lane = tid & 63;
    const int wv   = tid >> 6;
    const int ln   = lane & 15;
    const int quad = lane >> 4;
    const int row0 = blockIdx.x * 64 + wv * 16;
    const int arow = row0 + ln;
    const bool aok = arow < NN;

    floatx4 acc[8] = {};

#pragma unroll
    for (int kc = 0; kc < 4; kc++) {
        const int k0 = kc * 32 + quad * 8;
        bf16x8 a_hi = zero8(), a_lo = zero8(), a_x = zero8();
        if (aok) {
            const floatx4 f0 = *(const floatx4*)(aggr + arow * 128 + k0);
            const floatx4 f1 = *(const floatx4*)(aggr + arow * 128 + k0 + 4);
            split8(f0, f1, a_hi, a_lo);
            const floatx4 g0 = *(const floatx4*)(x + arow * 128 + k0);
            const floatx4 g1 = *(const floatx4*)(x + arow * 128 + k0 + 4);
            a_x = cvt8(g0, g1);
        }
#pragma unroll
        for (int nc = 0; nc < 8; nc++) {
            const bf16x8 bw  = *(const bf16x8*)(wl_s  + (nc * 16 + ln) * 136 + k0);
            const bf16x8 bw2 = *(const bf16x8*)(w01_s + (nc * 16 + ln) * 136 + k0);
            acc[nc] = __builtin_amdgcn_mfma_f32_16x16x32_bf16(a_hi, bw,  acc[nc], 0, 0, 0);
            acc[nc] = __builtin_amdgcn_mfma_f32_16x16x32_bf16(a_lo, bw,  acc[nc], 0, 0, 0);
            acc[nc] = __builtin_amdgcn_mfma_f32_16x16x32_bf16(a_x,  bw2, acc[nc], 0, 0, 0);
        }
    }

#pragma unroll
    for (int nc = 0; nc < 8; nc++) {
        const int col = nc * 16 + ln;
        const float bv = bias_s[col];
#pragma unroll
        for (int r = 0; r < 4; r++) {
            const int row = row0 + quad * 4 + r;
            if (row < NN) {
                float v = acc[nc][r] + bv;
                hout[row * 128 + col] = (v > 0.f ? v : 0.f);
            }
        }
    }
}

// ---------------- GEMM2 (MFMA): out = h @ ow^T + ob, in-place over d_out ----------------
// Each wave reads exactly the 16 rows it later writes (program-order safe in-place).
__global__ __launch_bounds__(256) void k_gemm2(
    const float* __restrict__ h, const float* __restrict__ ow, const float* __restrict__ ob,
    float* __restrict__ out)
{
    __shared__ bf16 ow_s[128 * 136];
    __shared__ float ob_s[128];
    const int tid = threadIdx.x;

#pragma unroll
    for (int it = 0; it < 8; it++) {
        int i = tid + it * 256;
        int r = i >> 4;
        int o = (i & 15) << 3;
        const floatx4 l0 = *(const floatx4*)(ow + r * 128 + o);
        const floatx4 l1 = *(const floatx4*)(ow + r * 128 + o + 4);
        *(bf16x8*)(ow_s + r * 136 + o) = cvt8(l0, l1);
    }
    if (tid < 128) ob_s[tid] = ob[tid];
    __syncthreads();

    const int lane = tid & 63;
    const int wv   = tid >> 6;
    const int ln   = lane & 15;
    const int quad = lane >> 4;
    const int row0 = blockIdx.x * 64 + wv * 16;
    const int arow = row0 + ln;
    const bool aok = arow < NN;

    floatx4 acc[8] = {};

#pragma unroll
    for (int kc = 0; kc < 4; kc++) {
        const int k0 = kc * 32 + quad * 8;
        bf16x8 a_hi = zero8(), a_lo = zero8();
        if (aok) {
            const floatx4 f0 = *(const floatx4*)(h + arow * 128 + k0);
            const floatx4 f1 = *(const floatx4*)(h + arow * 128 + k0 + 4);
            split8(f0, f1, a_hi, a_lo);
        }
#pragma unroll
        for (int nc = 0; nc < 8; nc++) {
            const bf16x8 bw = *(const bf16x8*)(ow_s + (nc * 16 + ln) * 136 + k0);
            acc[nc] = __builtin_amdgcn_mfma_f32_16x16x32_bf16(a_hi, bw, acc[nc], 0, 0, 0);
            acc[nc] = __builtin_amdgcn_mfma_f32_16x16x32_bf16(a_lo, bw, acc[nc], 0, 0, 0);
        }
    }

#pragma unroll
    for (int nc = 0; nc < 8; nc++) {
        const int col = nc * 16 + ln;
        const float bv = ob_s[col];
#pragma unroll
        for (int r = 0; r < 4; r++) {
            const int row = row0 + quad * 4 + r;
            if (row < NN) {
                out[row * 128 + col] = acc[nc][r] + bv;
            }
        }
    }
}

extern "C" void kernel_launch(void* const* d_in, const int* in_sizes, int n_in,
                              void* d_out, int out_size, void* d_ws, size_t ws_size,
                              hipStream_t stream) {
    // Inputs f32, indices int32, output f32 (R5 probe + R6 pass). Dead inputs skipped.
    const float* x_a     = (const float*)d_in[0];
    const int*   edge_ba = (const int*)d_in[3];
    const float* c1_w0_w = (const float*)d_in[10];
    const float* c1_w0_b = (const float*)d_in[11];
    const float* c1_wl_w = (const float*)d_in[12];
    const float* c1_wl_b = (const float*)d_in[13];
    const float* c1_w1_w = (const float*)d_in[14];
    const float* c1_w1_b = (const float*)d_in[15];
    const float* out_w   = (const float*)d_in[16];
    const float* out_b   = (const float*)d_in[17];

    float* aggr = (float*)d_ws;     // N*H f32 (25.6 MB)
    float* hbuf = (float*)d_out;    // h_a (f32) in d_out; GEMM2 row-local in-place

    k_zero   <<<NN * HD / 4 / 256, 256, 0, stream>>>(aggr);
    k_scatter<<<NE * 32 / 256,     256, 0, stream>>>(x_a, edge_ba, aggr);
    k_gemm1  <<<(NN + 63) / 64,    256, 0, stream>>>(aggr, x_a, c1_wl_w, c1_w0_w, c1_w1_w,
                                                     c1_wl_b, c1_w0_b, c1_w1_b, hbuf);
    k_gemm2  <<<(NN + 63) / 64,    256, 0, stream>>>(hbuf, out_w, out_b, (float*)d_out);
}

// Round 8
// 365.079 us; speedup vs baseline: 7.4417x; 2.7173x over previous
//
#include <hip/hip_runtime.h>
#include <hip/hip_bf16.h>

#define NN 50000
#define NE 500000
#define HD 128

typedef __bf16 bf16;
typedef __attribute__((ext_vector_type(8))) __bf16 bf16x8;
typedef __attribute__((ext_vector_type(4))) float floatx4;

__device__ inline bf16x8 cvt8(floatx4 a, floatx4 b) {
    bf16x8 r;
#pragma unroll
    for (int j = 0; j < 4; j++) { r[j] = (bf16)a[j]; r[j + 4] = (bf16)b[j]; }
    return r;
}

__device__ inline void split8(const floatx4 f0, const floatx4 f1, bf16x8& hi, bf16x8& lo) {
#pragma unroll
    for (int j = 0; j < 4; j++) {
        float a = f0[j]; bf16 h = (bf16)a; hi[j] = h; lo[j] = (bf16)(a - (float)h);
        float b = f1[j]; bf16 g = (bf16)b; hi[j + 4] = g; lo[j + 4] = (bf16)(b - (float)g);
    }
}

__device__ inline bf16x8 zero8() {
    bf16x8 v;
#pragma unroll
    for (int j = 0; j < 8; j++) v[j] = (bf16)0.f;
    return v;
}

// ================= CSR build =================
__global__ __launch_bounds__(256) void k_zero_i(int* __restrict__ p, int n) {
    int i = blockIdx.x * 256 + threadIdx.x;
    if (i < n) p[i] = 0;
}

// degree histogram (int atomics, L2-native)
__global__ __launch_bounds__(256) void k_hist(const int* __restrict__ edge,
                                              int* __restrict__ cnt) {
    int e = blockIdx.x * 256 + threadIdx.x;
    if (e < NE) atomicAdd(&cnt[edge[e]], 1);
}

// single-block exclusive scan of 50000 degrees -> offsets[NN+1], cursors
// cnt and cur may alias (read-before-write per element, phases barrier-separated).
__global__ __launch_bounds__(1024) void k_scan(const int* __restrict__ cnt,
                                               int* __restrict__ offs,
                                               int* __restrict__ cur) {
    __shared__ int partial[1024];
    const int t = threadIdx.x;
    const int CH = (NN + 1023) / 1024;  // 49
    const int base = t * CH;
    int sum = 0;
    for (int i = 0; i < CH; i++) {
        int idx = base + i;
        if (idx < NN) sum += cnt[idx];
    }
    partial[t] = sum;
    __syncthreads();
    for (int off = 1; off < 1024; off <<= 1) {
        int v = (t >= off) ? partial[t - off] : 0;
        __syncthreads();
        partial[t] += v;
        __syncthreads();
    }
    int run = (t > 0) ? partial[t - 1] : 0;
    for (int i = 0; i < CH; i++) {
        int idx = base + i;
        if (idx < NN) {
            int c = cnt[idx];
            offs[idx] = run;
            cur[idx] = run;
            run += c;
        }
    }
    if (t == 1023) offs[NN] = NE;
}

// scatter edge sources into CSR slots
__global__ __launch_bounds__(256) void k_fill(const int* __restrict__ edge,
                                              int* __restrict__ cur,
                                              int* __restrict__ csr_src) {
    int e = blockIdx.x * 256 + threadIdx.x;
    if (e < NE) {
        int dst = edge[e];
        int src = edge[NE + e];
        int pos = atomicAdd(&cur[dst], 1);
        csr_src[pos] = src;
    }
}

// gather-aggregate: one wave per node, lane = 2 features (float2).
__global__ __launch_bounds__(256) void k_aggr(const float* __restrict__ x,
                                              const int* __restrict__ offs,
                                              const int* __restrict__ csr_src,
                                              float* __restrict__ aggr) {
    int w = (blockIdx.x * 256 + threadIdx.x) >> 6;   // node id
    int lane = threadIdx.x & 63;
    if (w >= NN) return;
    int s = offs[w], e = offs[w + 1];
    const float2* xp = (const float2*)x;
    float ax = 0.f, ay = 0.f;
    int d = s;
    for (; d + 1 < e; d += 2) {           // 2-way unroll: overlap the two gathers
        int s0 = csr_src[d], s1 = csr_src[d + 1];
        float2 v0 = xp[(size_t)s0 * 64 + lane];
        float2 v1 = xp[(size_t)s1 * 64 + lane];
        ax += v0.x + v1.x; ay += v0.y + v1.y;
    }
    if (d < e) {
        float2 v = xp[(size_t)csr_src[d] * 64 + lane];
        ax += v.x; ay += v.y;
    }
    float2 o; o.x = ax; o.y = ay;
    ((float2*)aggr)[(size_t)w * 64 + lane] = o;
}

// ================= fallback atomic path (proven, used if ws too small) ============
__global__ __launch_bounds__(256) void k_zero(float* __restrict__ p) {
    int i = blockIdx.x * 256 + threadIdx.x;
    floatx4 z = {0.f, 0.f, 0.f, 0.f};
    ((floatx4*)p)[i] = z;
}

__global__ __launch_bounds__(256) void k_scatter(const float* __restrict__ x,
                                                 const int* __restrict__ edge,
                                                 float* __restrict__ aggr) {
    int tid = blockIdx.x * 256 + threadIdx.x;
    int e = tid >> 5;
    int c = (tid & 31) << 2;
    int dst = edge[e];
    int src = edge[NE + e];
    const floatx4 v = *(const floatx4*)(x + src * HD + c);
    float* ap = aggr + dst * HD + c;
    unsafeAtomicAdd(ap + 0, v[0]);
    unsafeAtomicAdd(ap + 1, v[1]);
    unsafeAtomicAdd(ap + 2, v[2]);
    unsafeAtomicAdd(ap + 3, v[3]);
}

// ================= GEMM1 (MFMA): h = relu(aggr@wl^T + x@(w0+w1)^T + bias) ============
__global__ __launch_bounds__(256) void k_gemm1(
    const float* __restrict__ aggr, const float* __restrict__ x,
    const float* __restrict__ wl, const float* __restrict__ w0, const float* __restrict__ w1,
    const float* __restrict__ bl, const float* __restrict__ b0, const float* __restrict__ b1,
    float* __restrict__ hout)
{
    __shared__ bf16 wl_s[128 * 136];
    __shared__ bf16 w01_s[128 * 136];
    __shared__ float bias_s[128];
    const int tid = threadIdx.x;

#pragma unroll
    for (int it = 0; it < 8; it++) {
        int i = tid + it * 256;
        int r = i >> 4;
        int o = (i & 15) << 3;
        const floatx4 l0 = *(const floatx4*)(wl + r * 128 + o);
        const floatx4 l1 = *(const floatx4*)(wl + r * 128 + o + 4);
        *(bf16x8*)(wl_s + r * 136 + o) = cvt8(l0, l1);
        floatx4 s0 = *(const floatx4*)(w0 + r * 128 + o);
        floatx4 s1 = *(const floatx4*)(w0 + r * 128 + o + 4);
        const floatx4 t0 = *(const floatx4*)(w1 + r * 128 + o);
        const floatx4 t1 = *(const floatx4*)(w1 + r * 128 + o + 4);
#pragma unroll
        for (int j = 0; j < 4; j++) { s0[j] += t0[j]; s1[j] += t1[j]; }
        *(bf16x8*)(w01_s + r * 136 + o) = cvt8(s0, s1);
    }
    if (tid < 128) bias_s[tid] = bl[tid] + b0[tid] + b1[tid];
    __syncthreads();

    const int lane = tid & 63;
    const int wv   = tid >> 6;
    const int ln   = lane & 15;
    const int quad = lane >> 4;
    const int row0 = blockIdx.x * 64 + wv * 16;
    const int arow = row0 + ln;
    const bool aok = arow < NN;

    floatx4 acc[8] = {};

#pragma unroll
    for (int kc = 0; kc < 4; kc++) {
        const int k0 = kc * 32 + quad * 8;
        bf16x8 a_hi = zero8(), a_lo = zero8(), a_x = zero8();
        if (aok) {
            const floatx4 f0 = *(const floatx4*)(aggr + arow * 128 + k0);
            const floatx4 f1 = *(const floatx4*)(aggr + arow * 128 + k0 + 4);
            split8(f0, f1, a_hi, a_lo);
            const floatx4 g0 = *(const floatx4*)(x + arow * 128 + k0);
            const floatx4 g1 = *(const floatx4*)(x + arow * 128 + k0 + 4);
            a_x = cvt8(g0, g1);
        }
#pragma unroll
        for (int nc = 0; nc < 8; nc++) {
            const bf16x8 bw  = *(const bf16x8*)(wl_s  + (nc * 16 + ln) * 136 + k0);
            const bf16x8 bw2 = *(const bf16x8*)(w01_s + (nc * 16 + ln) * 136 + k0);
            acc[nc] = __builtin_amdgcn_mfma_f32_16x16x32_bf16(a_hi, bw,  acc[nc], 0, 0, 0);
            acc[nc] = __builtin_amdgcn_mfma_f32_16x16x32_bf16(a_lo, bw,  acc[nc], 0, 0, 0);
            acc[nc] = __builtin_amdgcn_mfma_f32_16x16x32_bf16(a_x,  bw2, acc[nc], 0, 0, 0);
        }
    }

#pragma unroll
    for (int nc = 0; nc < 8; nc++) {
        const int col = nc * 16 + ln;
        const float bv = bias_s[col];
#pragma unroll
        for (int r = 0; r < 4; r++) {
            const int row = row0 + quad * 4 + r;
            if (row < NN) {
                float v = acc[nc][r] + bv;
                hout[row * 128 + col] = (v > 0.f ? v : 0.f);
            }
        }
    }
}

// ================= GEMM2 (MFMA): out = h @ ow^T + ob, row-local in-place ============
__global__ __launch_bounds__(256) void k_gemm2(
    const float* __restrict__ h, const float* __restrict__ ow, const float* __restrict__ ob,
    float* __restrict__ out)
{
    __shared__ bf16 ow_s[128 * 136];
    __shared__ float ob_s[128];
    const int tid = threadIdx.x;

#pragma unroll
    for (int it = 0; it < 8; it++) {
        int i = tid + it * 256;
        int r = i >> 4;
        int o = (i & 15) << 3;
        const floatx4 l0 = *(const floatx4*)(ow + r * 128 + o);
        const floatx4 l1 = *(const floatx4*)(ow + r * 128 + o + 4);
        *(bf16x8*)(ow_s + r * 136 + o) = cvt8(l0, l1);
    }
    if (tid < 128) ob_s[tid] = ob[tid];
    __syncthreads();

    const int lane = tid & 63;
    const int wv   = tid >> 6;
    const int ln   = lane & 15;
    const int quad = lane >> 4;
    const int row0 = blockIdx.x * 64 + wv * 16;
    const int arow = row0 + ln;
    const bool aok = arow < NN;

    floatx4 acc[8] = {};

#pragma unroll
    for (int kc = 0; kc < 4; kc++) {
        const int k0 = kc * 32 + quad * 8;
        bf16x8 a_hi = zero8(), a_lo = zero8();
        if (aok) {
            const floatx4 f0 = *(const floatx4*)(h + arow * 128 + k0);
            const floatx4 f1 = *(const floatx4*)(h + arow * 128 + k0 + 4);
            split8(f0, f1, a_hi, a_lo);
        }
#pragma unroll
        for (int nc = 0; nc < 8; nc++) {
            const bf16x8 bw = *(const bf16x8*)(ow_s + (nc * 16 + ln) * 136 + k0);
            acc[nc] = __builtin_amdgcn_mfma_f32_16x16x32_bf16(a_hi, bw, acc[nc], 0, 0, 0);
            acc[nc] = __builtin_amdgcn_mfma_f32_16x16x32_bf16(a_lo, bw, acc[nc], 0, 0, 0);
        }
    }

#pragma unroll
    for (int nc = 0; nc < 8; nc++) {
        const int col = nc * 16 + ln;
        const float bv = ob_s[col];
#pragma unroll
        for (int r = 0; r < 4; r++) {
            const int row = row0 + quad * 4 + r;
            if (row < NN) {
                out[row * 128 + col] = acc[nc][r] + bv;
            }
        }
    }
}

extern "C" void kernel_launch(void* const* d_in, const int* in_sizes, int n_in,
                              void* d_out, int out_size, void* d_ws, size_t ws_size,
                              hipStream_t stream) {
    const float* x_a     = (const float*)d_in[0];
    const int*   edge_ba = (const int*)d_in[3];
    const float* c1_w0_w = (const float*)d_in[10];
    const float* c1_w0_b = (const float*)d_in[11];
    const float* c1_wl_w = (const float*)d_in[12];
    const float* c1_wl_b = (const float*)d_in[13];
    const float* c1_w1_w = (const float*)d_in[14];
    const float* c1_w1_b = (const float*)d_in[15];
    const float* out_w   = (const float*)d_in[16];
    const float* out_b   = (const float*)d_in[17];

    // ws layout
    const size_t AGGR_B = (size_t)NN * HD * 4;                 // 25,600,000
    float* aggr = (float*)d_ws;
    int* offs   = (int*)((char*)d_ws + AGGR_B);                //  (NN+1) ints
    int* dcur   = (int*)((char*)d_ws + AGGR_B + 200004);       //  NN ints (counts, then cursors)
    int* csr    = (int*)((char*)d_ws + AGGR_B + 400004);       //  NE ints
    const size_t WS_NEED = AGGR_B + 400004 + (size_t)NE * 4;   //  ~28.0 MB

    float* hbuf = (float*)d_out;

    if (ws_size >= WS_NEED) {
        // CSR build + gather aggregation (no f32 atomics, no 1 GB writeback)
        k_zero_i<<<(NN + 255) / 256, 256, 0, stream>>>(dcur, NN);
        k_hist  <<<(NE + 255) / 256, 256, 0, stream>>>(edge_ba, dcur);
        k_scan  <<<1, 1024, 0, stream>>>(dcur, offs, dcur);
        k_fill  <<<(NE + 255) / 256, 256, 0, stream>>>(edge_ba, dcur, csr);
        k_aggr  <<<(NN * 64 + 255) / 256, 256, 0, stream>>>(x_a, offs, csr, aggr);
    } else {
        // fallback: proven atomic scatter
        k_zero   <<<NN * HD / 4 / 256, 256, 0, stream>>>(aggr);
        k_scatter<<<NE * 32 / 256,     256, 0, stream>>>(x_a, edge_ba, aggr);
    }

    k_gemm1<<<(NN + 63) / 64, 256, 0, stream>>>(aggr, x_a, c1_wl_w, c1_w0_w, c1_w1_w,
                                                c1_wl_b, c1_w0_b, c1_w1_b, hbuf);
    k_gemm2<<<(NN + 63) / 64, 256, 0, stream>>>(hbuf, out_w, out_b, (float*)d_out);
}

// Round 9
// 243.441 us; speedup vs baseline: 11.1600x; 1.4997x over previous
//
#include <hip/hip_runtime.h>
#include <hip/hip_bf16.h>

#define NN 50000
#define NE 500000
#define HD 128
#define SCAN_B ((NN + 255) / 256)   // 196

typedef __bf16 bf16;
typedef __attribute__((ext_vector_type(8))) __bf16 bf16x8;
typedef __attribute__((ext_vector_type(4))) float floatx4;

__device__ inline bf16x8 cvt8(floatx4 a, floatx4 b) {
    bf16x8 r;
#pragma unroll
    for (int j = 0; j < 4; j++) { r[j] = (bf16)a[j]; r[j + 4] = (bf16)b[j]; }
    return r;
}

__device__ inline void split8(const floatx4 f0, const floatx4 f1, bf16x8& hi, bf16x8& lo) {
#pragma unroll
    for (int j = 0; j < 4; j++) {
        float a = f0[j]; bf16 h = (bf16)a; hi[j] = h; lo[j] = (bf16)(a - (float)h);
        float b = f1[j]; bf16 g = (bf16)b; hi[j + 4] = g; lo[j + 4] = (bf16)(b - (float)g);
    }
}

__device__ inline bf16x8 zero8() {
    bf16x8 v;
#pragma unroll
    for (int j = 0; j < 8; j++) v[j] = (bf16)0.f;
    return v;
}

// ============ weight pre-conversion (once per launch, 24 blocks) ============
__global__ __launch_bounds__(256) void k_prep(
    const float* __restrict__ wl, const float* __restrict__ w0, const float* __restrict__ w1,
    const float* __restrict__ bl, const float* __restrict__ b0, const float* __restrict__ b1,
    const float* __restrict__ ow, const float* __restrict__ ob,
    bf16* __restrict__ wlb, bf16* __restrict__ w01b, bf16* __restrict__ owb,
    float* __restrict__ bias1, float* __restrict__ bias2)
{
    int g = blockIdx.x * 256 + threadIdx.x;   // 6144 chunks of 8 elements
    int m = g >> 11, off = (g & 2047) << 3;
    if (m == 0) {
        const floatx4 a = *(const floatx4*)(wl + off);
        const floatx4 b = *(const floatx4*)(wl + off + 4);
        *(bf16x8*)(wlb + off) = cvt8(a, b);
    } else if (m == 1) {
        floatx4 a = *(const floatx4*)(w0 + off);
        floatx4 b = *(const floatx4*)(w0 + off + 4);
        const floatx4 c = *(const floatx4*)(w1 + off);
        const floatx4 d = *(const floatx4*)(w1 + off + 4);
#pragma unroll
        for (int j = 0; j < 4; j++) { a[j] += c[j]; b[j] += d[j]; }
        *(bf16x8*)(w01b + off) = cvt8(a, b);
    } else {
        const floatx4 a = *(const floatx4*)(ow + off);
        const floatx4 b = *(const floatx4*)(ow + off + 4);
        *(bf16x8*)(owb + off) = cvt8(a, b);
    }
    if (g < 128) bias1[g] = bl[g] + b0[g] + b1[g];
    else if (g < 256) bias2[g - 128] = ob[g - 128];
}

// ================= CSR build =================
__global__ __launch_bounds__(256) void k_zero_i(int* __restrict__ p, int n) {
    int i = blockIdx.x * 256 + threadIdx.x;
    if (i < n) p[i] = 0;
}

__global__ __launch_bounds__(256) void k_hist(const int* __restrict__ edge,
                                              int* __restrict__ cnt) {
    int e = blockIdx.x * 256 + threadIdx.x;
    if (e < NE) atomicAdd(&cnt[edge[e]], 1);
}

// hierarchical scan, stage 1: per-block exclusive scan + block sums
__global__ __launch_bounds__(256) void k_scan1(const int* __restrict__ cnt,
                                               int* __restrict__ excl,   // = offs
                                               int* __restrict__ bsum) {
    __shared__ int s[256];
    const int t = threadIdx.x, i = blockIdx.x * 256 + t;
    int c = (i < NN) ? cnt[i] : 0;
    s[t] = c; __syncthreads();
    int v = c;
    for (int off = 1; off < 256; off <<= 1) {
        int u = (t >= off) ? s[t - off] : 0;
        __syncthreads();
        v += u; s[t] = v;
        __syncthreads();
    }
    if (i < NN) excl[i] = v - c;
    if (t == 255) bsum[blockIdx.x] = v;
}

// stage 2: exclusive scan of the 196 block sums (in-place), single block
__global__ __launch_bounds__(256) void k_scan2(int* __restrict__ bsum) {
    __shared__ int s[256];
    const int t = threadIdx.x;
    int c = (t < SCAN_B) ? bsum[t] : 0;
    s[t] = c; __syncthreads();
    int v = c;
    for (int off = 1; off < 256; off <<= 1) {
        int u = (t >= off) ? s[t - off] : 0;
        __syncthreads();
        v += u; s[t] = v;
        __syncthreads();
    }
    if (t < SCAN_B) bsum[t] = v - c;
}

// stage 3: add block offset, emit offs + cursors
__global__ __launch_bounds__(256) void k_scan3(int* __restrict__ offs,
                                               const int* __restrict__ bsum,
                                               int* __restrict__ cur) {
    int i = blockIdx.x * 256 + threadIdx.x;
    if (i < NN) {
        int o = offs[i] + bsum[blockIdx.x];
        offs[i] = o;
        cur[i] = o;
    } else if (i == NN) {
        offs[NN] = NE;
    }
}

__global__ __launch_bounds__(256) void k_fill(const int* __restrict__ edge,
                                              int* __restrict__ cur,
                                              int* __restrict__ csr_src) {
    int e = blockIdx.x * 256 + threadIdx.x;
    if (e < NE) {
        int dst = edge[e];
        int src = edge[NE + e];
        int pos = atomicAdd(&cur[dst], 1);
        csr_src[pos] = src;
    }
}

// gather-aggregate: one wave per node, lane = 2 features (float2)
__global__ __launch_bounds__(256) void k_aggr(const float* __restrict__ x,
                                              const int* __restrict__ offs,
                                              const int* __restrict__ csr_src,
                                              float* __restrict__ aggr) {
    int w = (blockIdx.x * 256 + threadIdx.x) >> 6;
    int lane = threadIdx.x & 63;
    if (w >= NN) return;
    int s = offs[w], e = offs[w + 1];
    const float2* xp = (const float2*)x;
    float ax = 0.f, ay = 0.f;
    int d = s;
    for (; d + 1 < e; d += 2) {
        int s0 = csr_src[d], s1 = csr_src[d + 1];
        float2 v0 = xp[(size_t)s0 * 64 + lane];
        float2 v1 = xp[(size_t)s1 * 64 + lane];
        ax += v0.x + v1.x; ay += v0.y + v1.y;
    }
    if (d < e) {
        float2 v = xp[(size_t)csr_src[d] * 64 + lane];
        ax += v.x; ay += v.y;
    }
    float2 o; o.x = ax; o.y = ay;
    ((float2*)aggr)[(size_t)w * 64 + lane] = o;
}

// ================= fallback atomic path (proven) ============
__global__ __launch_bounds__(256) void k_zero(float* __restrict__ p) {
    int i = blockIdx.x * 256 + threadIdx.x;
    floatx4 z = {0.f, 0.f, 0.f, 0.f};
    ((floatx4*)p)[i] = z;
}

__global__ __launch_bounds__(256) void k_scatter(const float* __restrict__ x,
                                                 const int* __restrict__ edge,
                                                 float* __restrict__ aggr) {
    int tid = blockIdx.x * 256 + threadIdx.x;
    int e = tid >> 5;
    int c = (tid & 31) << 2;
    int dst = edge[e];
    int src = edge[NE + e];
    const floatx4 v = *(const floatx4*)(x + src * HD + c);
    float* ap = aggr + dst * HD + c;
    unsafeAtomicAdd(ap + 0, v[0]);
    unsafeAtomicAdd(ap + 1, v[1]);
    unsafeAtomicAdd(ap + 2, v[2]);
    unsafeAtomicAdd(ap + 3, v[3]);
}

// ====== GEMM1 (MFMA, preconverted bf16 weights): h = relu(aggr@wl^T + x@w01^T + bias) ======
__global__ __launch_bounds__(256) void k_gemm1(
    const float* __restrict__ aggr, const float* __restrict__ x,
    const bf16* __restrict__ wlb, const bf16* __restrict__ w01b,
    const float* __restrict__ bias1,
    float* __restrict__ hout)
{
    __shared__ bf16 wl_s[128 * 136];
    __shared__ bf16 w01_s[128 * 136];
    __shared__ float bias_s[128];
    const int tid = threadIdx.x;

#pragma unroll
    for (int it = 0; it < 8; it++) {
        int i = tid + it * 256;          // 2048 chunks of 8
        int r = i >> 4;
        int o = (i & 15) << 3;
        *(bf16x8*)(wl_s  + r * 136 + o) = *(const bf16x8*)(wlb  + r * 128 + o);
        *(bf16x8*)(w01_s + r * 136 + o) = *(const bf16x8*)(w01b + r * 128 + o);
    }
    if (tid < 128) bias_s[tid] = bias1[tid];
    __syncthreads();

    const int lane = tid & 63;
    const int wv   = tid >> 6;
    const int ln   = lane & 15;
    const int quad = lane >> 4;
    const int row0 = blockIdx.x * 64 + wv * 16;
    const int arow = row0 + ln;
    const bool aok = arow < NN;

    floatx4 acc[8] = {};

#pragma unroll
    for (int kc = 0; kc < 4; kc++) {
        const int k0 = kc * 32 + quad * 8;
        bf16x8 a_hi = zero8(), a_lo = zero8(), a_x = zero8();
        if (aok) {
            const floatx4 f0 = *(const floatx4*)(aggr + arow * 128 + k0);
            const floatx4 f1 = *(const floatx4*)(aggr + arow * 128 + k0 + 4);
            split8(f0, f1, a_hi, a_lo);
            const floatx4 g0 = *(const floatx4*)(x + arow * 128 + k0);
            const floatx4 g1 = *(const floatx4*)(x + arow * 128 + k0 + 4);
            a_x = cvt8(g0, g1);
        }
#pragma unroll
        for (int nc = 0; nc < 8; nc++) {
            const bf16x8 bw  = *(const bf16x8*)(wl_s  + (nc * 16 + ln) * 136 + k0);
            const bf16x8 bw2 = *(const bf16x8*)(w01_s + (nc * 16 + ln) * 136 + k0);
            acc[nc] = __builtin_amdgcn_mfma_f32_16x16x32_bf16(a_hi, bw,  acc[nc], 0, 0, 0);
            acc[nc] = __builtin_amdgcn_mfma_f32_16x16x32_bf16(a_lo, bw,  acc[nc], 0, 0, 0);
            acc[nc] = __builtin_amdgcn_mfma_f32_16x16x32_bf16(a_x,  bw2, acc[nc], 0, 0, 0);
        }
    }

#pragma unroll
    for (int nc = 0; nc < 8; nc++) {
        const int col = nc * 16 + ln;
        const float bv = bias_s[col];
#pragma unroll
        for (int r = 0; r < 4; r++) {
            const int row = row0 + quad * 4 + r;
            if (row < NN) {
                float v = acc[nc][r] + bv;
                hout[row * 128 + col] = (v > 0.f ? v : 0.f);
            }
        }
    }
}

// ====== GEMM2 (MFMA, preconverted): out = h @ ow^T + ob, row-local in-place ======
__global__ __launch_bounds__(256) void k_gemm2(
    const float* __restrict__ h, const bf16* __restrict__ owb,
    const float* __restrict__ bias2,
    float* __restrict__ out)
{
    __shared__ bf16 ow_s[128 * 136];
    __shared__ float ob_s[128];
    const int tid = threadIdx.x;

#pragma unroll
    for (int it = 0; it < 8; it++) {
        int i = tid + it * 256;
        int r = i >> 4;
        int o = (i & 15) << 3;
        *(bf16x8*)(ow_s + r * 136 + o) = *(const bf16x8*)(owb + r * 128 + o);
    }
    if (tid < 128) ob_s[tid] = bias2[tid];
    __syncthreads();

    const int lane = tid & 63;
    const int wv   = tid >> 6;
    const int ln   = lane & 15;
    const int quad = lane >> 4;
    const int row0 = blockIdx.x * 64 + wv * 16;
    const int arow = row0 + ln;
    const bool aok = arow < NN;

    floatx4 acc[8] = {};

#pragma unroll
    for (int kc = 0; kc < 4; kc++) {
        const int k0 = kc * 32 + quad * 8;
        bf16x8 a_hi = zero8(), a_lo = zero8();
        if (aok) {
            const floatx4 f0 = *(const floatx4*)(h + arow * 128 + k0);
            const floatx4 f1 = *(const floatx4*)(h + arow * 128 + k0 + 4);
            split8(f0, f1, a_hi, a_lo);
        }
#pragma unroll
        for (int nc = 0; nc < 8; nc++) {
            const bf16x8 bw = *(const bf16x8*)(ow_s + (nc * 16 + ln) * 136 + k0);
            acc[nc] = __builtin_amdgcn_mfma_f32_16x16x32_bf16(a_hi, bw, acc[nc], 0, 0, 0);
            acc[nc] = __builtin_amdgcn_mfma_f32_16x16x32_bf16(a_lo, bw, acc[nc], 0, 0, 0);
        }
    }

#pragma unroll
    for (int nc = 0; nc < 8; nc++) {
        const int col = nc * 16 + ln;
        const float bv = ob_s[col];
#pragma unroll
        for (int r = 0; r < 4; r++) {
            const int row = row0 + quad * 4 + r;
            if (row < NN) {
                out[row * 128 + col] = acc[nc][r] + bv;
            }
        }
    }
}

extern "C" void kernel_launch(void* const* d_in, const int* in_sizes, int n_in,
                              void* d_out, int out_size, void* d_ws, size_t ws_size,
                              hipStream_t stream) {
    const float* x_a     = (const float*)d_in[0];
    const int*   edge_ba = (const int*)d_in[3];
    const float* c1_w0_w = (const float*)d_in[10];
    const float* c1_w0_b = (const float*)d_in[11];
    const float* c1_wl_w = (const float*)d_in[12];
    const float* c1_wl_b = (const float*)d_in[13];
    const float* c1_w1_w = (const float*)d_in[14];
    const float* c1_w1_b = (const float*)d_in[15];
    const float* out_w   = (const float*)d_in[16];
    const float* out_b   = (const float*)d_in[17];

    // ws layout: prep buffers first (fallback needs only these), CSR after.
    char* p = (char*)d_ws;
    float* aggr  = (float*)p;                          p += (size_t)NN * HD * 4;  // 25.6 MB
    bf16*  wlb   = (bf16*)p;                           p += 32768;
    bf16*  w01b  = (bf16*)p;                           p += 32768;
    bf16*  owb   = (bf16*)p;                           p += 32768;
    float* bias1 = (float*)p;                          p += 512;
    float* bias2 = (float*)p;                          p += 512;
    const size_t WS_FALLBACK = (size_t)(p - (char*)d_ws);
    int*   offs  = (int*)p;                            p += 200064;  // NN+1 ints
    int*   dcur  = (int*)p;                            p += 200064;  // NN ints
    int*   csr   = (int*)p;                            p += (size_t)NE * 4;
    int*   bsum  = (int*)p;                            p += 1024;
    const size_t WS_NEED = (size_t)(p - (char*)d_ws);  // ~28.1 MB

    float* hbuf = (float*)d_out;

    k_prep<<<24, 256, 0, stream>>>(c1_wl_w, c1_w0_w, c1_w1_w, c1_wl_b, c1_w0_b, c1_w1_b,
                                   out_w, out_b, wlb, w01b, owb, bias1, bias2);

    if (ws_size >= WS_NEED) {
        k_zero_i<<<(NN + 255) / 256, 256, 0, stream>>>(dcur, NN);
        k_hist  <<<(NE + 255) / 256, 256, 0, stream>>>(edge_ba, dcur);
        k_scan1 <<<SCAN_B, 256, 0, stream>>>(dcur, offs, bsum);
        k_scan2 <<<1, 256, 0, stream>>>(bsum);
        k_scan3 <<<SCAN_B, 256, 0, stream>>>(offs, bsum, dcur);
        k_fill  <<<(NE + 255) / 256, 256, 0, stream>>>(edge_ba, dcur, csr);
        k_aggr  <<<(NN * 64 + 255) / 256, 256, 0, stream>>>(x_a, offs, csr, aggr);
    } else if (ws_size >= WS_FALLBACK) {
        k_zero   <<<NN * HD / 4 / 256, 256, 0, stream>>>(aggr);
        k_scatter<<<NE * 32 / 256,     256, 0, stream>>>(x_a, edge_ba, aggr);
    }

    k_gemm1<<<(NN + 63) / 64, 256, 0, stream>>>(aggr, x_a, wlb, w01b, bias1, hbuf);
    k_gemm2<<<(NN + 63) / 64, 256, 0, stream>>>(hbuf, owb, bias2, (float*)d_out);
}

// Round 10
// 241.261 us; speedup vs baseline: 11.2608x; 1.0090x over previous
//
#include <hip/hip_runtime.h>
#include <hip/hip_bf16.h>

#define NN 50000
#define NE 500000
#define HD 128
#define SCAN_B ((NN + 255) / 256)   // 196

typedef __bf16 bf16;
typedef __attribute__((ext_vector_type(8))) __bf16 bf16x8;
typedef __attribute__((ext_vector_type(4))) float floatx4;

__device__ inline float u2f(unsigned int lo16) {
    union { unsigned int i; float f; } c; c.i = lo16 << 16; return c.f;
}

__device__ inline bf16x8 cvt8(floatx4 a, floatx4 b) {
    bf16x8 r;
#pragma unroll
    for (int j = 0; j < 4; j++) { r[j] = (bf16)a[j]; r[j + 4] = (bf16)b[j]; }
    return r;
}

__device__ inline void split8(const floatx4 f0, const floatx4 f1, bf16x8& hi, bf16x8& lo) {
#pragma unroll
    for (int j = 0; j < 4; j++) {
        float a = f0[j]; bf16 h = (bf16)a; hi[j] = h; lo[j] = (bf16)(a - (float)h);
        float b = f1[j]; bf16 g = (bf16)b; hi[j + 4] = g; lo[j + 4] = (bf16)(b - (float)g);
    }
}

__device__ inline bf16x8 zero8() {
    bf16x8 v;
#pragma unroll
    for (int j = 0; j < 8; j++) v[j] = (bf16)0.f;
    return v;
}

// ============ weight pre-conversion ============
__global__ __launch_bounds__(256) void k_prep(
    const float* __restrict__ wl, const float* __restrict__ w0, const float* __restrict__ w1,
    const float* __restrict__ bl, const float* __restrict__ b0, const float* __restrict__ b1,
    const float* __restrict__ ow, const float* __restrict__ ob,
    bf16* __restrict__ wlb, bf16* __restrict__ w01b, bf16* __restrict__ owb,
    float* __restrict__ bias1, float* __restrict__ bias2)
{
    int g = blockIdx.x * 256 + threadIdx.x;
    int m = g >> 11, off = (g & 2047) << 3;
    if (m == 0) {
        const floatx4 a = *(const floatx4*)(wl + off);
        const floatx4 b = *(const floatx4*)(wl + off + 4);
        *(bf16x8*)(wlb + off) = cvt8(a, b);
    } else if (m == 1) {
        floatx4 a = *(const floatx4*)(w0 + off);
        floatx4 b = *(const floatx4*)(w0 + off + 4);
        const floatx4 c = *(const floatx4*)(w1 + off);
        const floatx4 d = *(const floatx4*)(w1 + off + 4);
#pragma unroll
        for (int j = 0; j < 4; j++) { a[j] += c[j]; b[j] += d[j]; }
        *(bf16x8*)(w01b + off) = cvt8(a, b);
    } else {
        const floatx4 a = *(const floatx4*)(ow + off);
        const floatx4 b = *(const floatx4*)(ow + off + 4);
        *(bf16x8*)(owb + off) = cvt8(a, b);
    }
    if (g < 128) bias1[g] = bl[g] + b0[g] + b1[g];
    else if (g < 256) bias2[g - 128] = ob[g - 128];
}

// ============ x -> bf16 (halves gather bytes) ============
__global__ __launch_bounds__(256) void k_prep_x(const float* __restrict__ x,
                                                bf16* __restrict__ xb) {
    int g = blockIdx.x * 256 + threadIdx.x;      // 800000 chunks of 8
    int off = g << 3;
    const floatx4 a = *(const floatx4*)(x + off);
    const floatx4 b = *(const floatx4*)(x + off + 4);
    *(bf16x8*)(xb + off) = cvt8(a, b);
}

// ================= CSR build =================
__global__ __launch_bounds__(256) void k_zero_i(int* __restrict__ p, int n) {
    int i = blockIdx.x * 256 + threadIdx.x;
    if (i < n) p[i] = 0;
}

__global__ __launch_bounds__(256) void k_hist(const int* __restrict__ edge,
                                              int* __restrict__ cnt) {
    int e = blockIdx.x * 256 + threadIdx.x;
    if (e < NE) atomicAdd(&cnt[edge[e]], 1);
}

__global__ __launch_bounds__(256) void k_scan1(const int* __restrict__ cnt,
                                               int* __restrict__ excl,
                                               int* __restrict__ bsum) {
    __shared__ int s[256];
    const int t = threadIdx.x, i = blockIdx.x * 256 + t;
    int c = (i < NN) ? cnt[i] : 0;
    s[t] = c; __syncthreads();
    int v = c;
    for (int off = 1; off < 256; off <<= 1) {
        int u = (t >= off) ? s[t - off] : 0;
        __syncthreads();
        v += u; s[t] = v;
        __syncthreads();
    }
    if (i < NN) excl[i] = v - c;
    if (t == 255) bsum[blockIdx.x] = v;
}

__global__ __launch_bounds__(256) void k_scan2(int* __restrict__ bsum) {
    __shared__ int s[256];
    const int t = threadIdx.x;
    int c = (t < SCAN_B) ? bsum[t] : 0;
    s[t] = c; __syncthreads();
    int v = c;
    for (int off = 1; off < 256; off <<= 1) {
        int u = (t >= off) ? s[t - off] : 0;
        __syncthreads();
        v += u; s[t] = v;
        __syncthreads();
    }
    if (t < SCAN_B) bsum[t] = v - c;
}

__global__ __launch_bounds__(256) void k_scan3(int* __restrict__ offs,
                                               const int* __restrict__ bsum,
                                               int* __restrict__ cur) {
    int i = blockIdx.x * 256 + threadIdx.x;
    if (i < NN) {
        int o = offs[i] + bsum[blockIdx.x];
        offs[i] = o;
        cur[i] = o;
    } else if (i == NN) {
        offs[NN] = NE;
    }
}

__global__ __launch_bounds__(256) void k_fill(const int* __restrict__ edge,
                                              int* __restrict__ cur,
                                              int* __restrict__ csr_src) {
    int e = blockIdx.x * 256 + threadIdx.x;
    if (e < NE) {
        int dst = edge[e];
        int src = edge[NE + e];
        int pos = atomicAdd(&cur[dst], 1);
        csr_src[pos] = src;
    }
}

// ======== gather-aggregate over bf16 x: wave per node, lane = 2 features ========
__global__ __launch_bounds__(256) void k_aggr_b(const unsigned int* __restrict__ xb2,
                                                const int* __restrict__ offs,
                                                const int* __restrict__ csr_src,
                                                float* __restrict__ aggr) {
    int w = (blockIdx.x * 256 + threadIdx.x) >> 6;
    int lane = threadIdx.x & 63;
    if (w >= NN) return;
    int s = offs[w], e = offs[w + 1];
    float ax = 0.f, ay = 0.f;
    int d = s;
    for (; d + 3 < e; d += 4) {
        int s0 = csr_src[d], s1 = csr_src[d + 1], s2 = csr_src[d + 2], s3 = csr_src[d + 3];
        unsigned int v0 = xb2[s0 * 64 + lane];
        unsigned int v1 = xb2[s1 * 64 + lane];
        unsigned int v2 = xb2[s2 * 64 + lane];
        unsigned int v3 = xb2[s3 * 64 + lane];
        ax += u2f(v0 & 0xffff) + u2f(v1 & 0xffff) + u2f(v2 & 0xffff) + u2f(v3 & 0xffff);
        ay += u2f(v0 >> 16) + u2f(v1 >> 16) + u2f(v2 >> 16) + u2f(v3 >> 16);
    }
    for (; d < e; d++) {
        unsigned int v = xb2[csr_src[d] * 64 + lane];
        ax += u2f(v & 0xffff); ay += u2f(v >> 16);
    }
    float2 o; o.x = ax; o.y = ay;
    ((float2*)aggr)[(size_t)w * 64 + lane] = o;
}

// ======== gather-aggregate f32 (tier-B, proven) ========
__global__ __launch_bounds__(256) void k_aggr_f(const float* __restrict__ x,
                                                const int* __restrict__ offs,
                                                const int* __restrict__ csr_src,
                                                float* __restrict__ aggr) {
    int w = (blockIdx.x * 256 + threadIdx.x) >> 6;
    int lane = threadIdx.x & 63;
    if (w >= NN) return;
    int s = offs[w], e = offs[w + 1];
    const float2* xp = (const float2*)x;
    float ax = 0.f, ay = 0.f;
    int d = s;
    for (; d + 1 < e; d += 2) {
        int s0 = csr_src[d], s1 = csr_src[d + 1];
        float2 v0 = xp[(size_t)s0 * 64 + lane];
        float2 v1 = xp[(size_t)s1 * 64 + lane];
        ax += v0.x + v1.x; ay += v0.y + v1.y;
    }
    if (d < e) {
        float2 v = xp[(size_t)csr_src[d] * 64 + lane];
        ax += v.x; ay += v.y;
    }
    float2 o; o.x = ax; o.y = ay;
    ((float2*)aggr)[(size_t)w * 64 + lane] = o;
}

// ======== fallback atomic path (tier-C, proven) ========
__global__ __launch_bounds__(256) void k_zero(float* __restrict__ p) {
    int i = blockIdx.x * 256 + threadIdx.x;
    floatx4 z = {0.f, 0.f, 0.f, 0.f};
    ((floatx4*)p)[i] = z;
}

__global__ __launch_bounds__(256) void k_scatter(const float* __restrict__ x,
                                                 const int* __restrict__ edge,
                                                 float* __restrict__ aggr) {
    int tid = blockIdx.x * 256 + threadIdx.x;
    int e = tid >> 5;
    int c = (tid & 31) << 2;
    int dst = edge[e];
    int src = edge[NE + e];
    const floatx4 v = *(const floatx4*)(x + src * HD + c);
    float* ap = aggr + dst * HD + c;
    unsafeAtomicAdd(ap + 0, v[0]);
    unsafeAtomicAdd(ap + 1, v[1]);
    unsafeAtomicAdd(ap + 2, v[2]);
    unsafeAtomicAdd(ap + 3, v[3]);
}

// ======== fused GEMM1+GEMM2 (row-local): out = relu(aggr@wl^T + x@w01^T + b1) @ ow^T + b2 ========
// 4 waves, 64 rows/block. h stays on-chip; C-layout -> A-layout via per-wave LDS transpose
// (stride 132 f32: writes 2-way bank alias, b128 reads 2-way — both free).
__global__ __launch_bounds__(256) void k_gemm12(
    const float* __restrict__ aggr, const float* __restrict__ x, const bf16* __restrict__ xb,
    int use_xb,
    const bf16* __restrict__ wlb, const bf16* __restrict__ w01b, const bf16* __restrict__ owb,
    const float* __restrict__ bias1, const float* __restrict__ bias2,
    float* __restrict__ out)
{
    __shared__ bf16 wl_s[128 * 136];
    __shared__ bf16 w01_s[128 * 136];
    __shared__ bf16 ow_s[128 * 136];
    __shared__ float tp[4][16][132];
    __shared__ float b1_s[128], b2_s[128];
    const int tid = threadIdx.x;

#pragma unroll
    for (int it = 0; it < 8; it++) {
        int i = tid + it * 256;
        int r = i >> 4;
        int o = (i & 15) << 3;
        *(bf16x8*)(wl_s  + r * 136 + o) = *(const bf16x8*)(wlb  + r * 128 + o);
        *(bf16x8*)(w01_s + r * 136 + o) = *(const bf16x8*)(w01b + r * 128 + o);
        *(bf16x8*)(ow_s  + r * 136 + o) = *(const bf16x8*)(owb  + r * 128 + o);
    }
    if (tid < 128) { b1_s[tid] = bias1[tid]; b2_s[tid] = bias2[tid]; }
    __syncthreads();

    const int lane = tid & 63;
    const int wv   = tid >> 6;
    const int ln   = lane & 15;
    const int quad = lane >> 4;
    const int row0 = blockIdx.x * 64 + wv * 16;
    const int arow = row0 + ln;
    const bool aok = arow < NN;

    floatx4 acc[8] = {};

    // ---- GEMM1 ----
#pragma unroll
    for (int kc = 0; kc < 4; kc++) {
        const int k0 = kc * 32 + quad * 8;
        bf16x8 a_hi = zero8(), a_lo = zero8(), a_x = zero8();
        if (aok) {
            const floatx4 f0 = *(const floatx4*)(aggr + arow * 128 + k0);
            const floatx4 f1 = *(const floatx4*)(aggr + arow * 128 + k0 + 4);
            split8(f0, f1, a_hi, a_lo);
            if (use_xb) {
                a_x = *(const bf16x8*)(xb + arow * 128 + k0);
            } else {
                const floatx4 g0 = *(const floatx4*)(x + arow * 128 + k0);
                const floatx4 g1 = *(const floatx4*)(x + arow * 128 + k0 + 4);
                a_x = cvt8(g0, g1);
            }
        }
#pragma unroll
        for (int nc = 0; nc < 8; nc++) {
            const bf16x8 bw  = *(const bf16x8*)(wl_s  + (nc * 16 + ln) * 136 + k0);
            const bf16x8 bw2 = *(const bf16x8*)(w01_s + (nc * 16 + ln) * 136 + k0);
            acc[nc] = __builtin_amdgcn_mfma_f32_16x16x32_bf16(a_hi, bw,  acc[nc], 0, 0, 0);
            acc[nc] = __builtin_amdgcn_mfma_f32_16x16x32_bf16(a_lo, bw,  acc[nc], 0, 0, 0);
            acc[nc] = __builtin_amdgcn_mfma_f32_16x16x32_bf16(a_x,  bw2, acc[nc], 0, 0, 0);
        }
    }

    // ---- bias + relu, park h in LDS (C-layout -> row-major) ----
#pragma unroll
    for (int nc = 0; nc < 8; nc++) {
        const int col = nc * 16 + ln;
        const float bv = b1_s[col];
#pragma unroll
        for (int r = 0; r < 4; r++) {
            float v = acc[nc][r] + bv;
            tp[wv][quad * 4 + r][col] = (v > 0.f ? v : 0.f);
        }
        acc[nc][0] = acc[nc][1] = acc[nc][2] = acc[nc][3] = 0.f;
    }
    __syncthreads();

    // ---- GEMM2: A-frags from tp (compensated hi/lo) ----
#pragma unroll
    for (int kc = 0; kc < 4; kc++) {
        const int k0 = kc * 32 + quad * 8;
        const floatx4 f0 = *(const floatx4*)(&tp[wv][ln][k0]);
        const floatx4 f1 = *(const floatx4*)(&tp[wv][ln][k0 + 4]);
        bf16x8 a_hi, a_lo;
        split8(f0, f1, a_hi, a_lo);
#pragma unroll
        for (int nc = 0; nc < 8; nc++) {
            const bf16x8 bw = *(const bf16x8*)(ow_s + (nc * 16 + ln) * 136 + k0);
            acc[nc] = __builtin_amdgcn_mfma_f32_16x16x32_bf16(a_hi, bw, acc[nc], 0, 0, 0);
            acc[nc] = __builtin_amdgcn_mfma_f32_16x16x32_bf16(a_lo, bw, acc[nc], 0, 0, 0);
        }
    }

#pragma unroll
    for (int nc = 0; nc < 8; nc++) {
        const int col = nc * 16 + ln;
        const float bv = b2_s[col];
#pragma unroll
        for (int r = 0; r < 4; r++) {
            const int row = row0 + quad * 4 + r;
            if (row < NN) out[row * 128 + col] = acc[nc][r] + bv;
        }
    }
}

extern "C" void kernel_launch(void* const* d_in, const int* in_sizes, int n_in,
                              void* d_out, int out_size, void* d_ws, size_t ws_size,
                              hipStream_t stream) {
    const float* x_a     = (const float*)d_in[0];
    const int*   edge_ba = (const int*)d_in[3];
    const float* c1_w0_w = (const float*)d_in[10];
    const float* c1_w0_b = (const float*)d_in[11];
    const float* c1_wl_w = (const float*)d_in[12];
    const float* c1_wl_b = (const float*)d_in[13];
    const float* c1_w1_w = (const float*)d_in[14];
    const float* c1_w1_b = (const float*)d_in[15];
    const float* out_w   = (const float*)d_in[16];
    const float* out_b   = (const float*)d_in[17];

    char* p = (char*)d_ws;
    float* aggr  = (float*)p;   p += (size_t)NN * HD * 4;   // 25.6 MB
    bf16*  wlb   = (bf16*)p;    p += 32768;
    bf16*  w01b  = (bf16*)p;    p += 32768;
    bf16*  owb   = (bf16*)p;    p += 32768;
    float* bias1 = (float*)p;   p += 512;
    float* bias2 = (float*)p;   p += 512;
    const size_t WS_FALL = (size_t)(p - (char*)d_ws);       // ~25.7 MB
    int*   offs  = (int*)p;     p += 200064;
    int*   dcur  = (int*)p;     p += 200064;
    int*   csr   = (int*)p;     p += (size_t)NE * 4;
    int*   bsum  = (int*)p;     p += 1024;
    const size_t WS_CSR = (size_t)(p - (char*)d_ws);        // ~28.1 MB
    bf16*  xb    = (bf16*)p;    p += (size_t)NN * HD * 2;   // 12.8 MB
    const size_t WS_FULL = (size_t)(p - (char*)d_ws);       // ~40.9 MB

    k_prep<<<24, 256, 0, stream>>>(c1_wl_w, c1_w0_w, c1_w1_w, c1_wl_b, c1_w0_b, c1_w1_b,
                                   out_w, out_b, wlb, w01b, owb, bias1, bias2);

    int use_xb = 0;
    if (ws_size >= WS_CSR) {
        k_zero_i<<<(NN + 255) / 256, 256, 0, stream>>>(dcur, NN);
        k_hist  <<<(NE + 255) / 256, 256, 0, stream>>>(edge_ba, dcur);
        k_scan1 <<<SCAN_B, 256, 0, stream>>>(dcur, offs, bsum);
        k_scan2 <<<1, 256, 0, stream>>>(bsum);
        k_scan3 <<<SCAN_B, 256, 0, stream>>>(offs, bsum, dcur);
        k_fill  <<<(NE + 255) / 256, 256, 0, stream>>>(edge_ba, dcur, csr);
        if (ws_size >= WS_FULL) {
            use_xb = 1;
            k_prep_x<<<3125, 256, 0, stream>>>(x_a, xb);
            k_aggr_b<<<(NN * 64 + 255) / 256, 256, 0, stream>>>((const unsigned int*)xb,
                                                                offs, csr, aggr);
        } else {
            k_aggr_f<<<(NN * 64 + 255) / 256, 256, 0, stream>>>(x_a, offs, csr, aggr);
        }
    } else if (ws_size >= WS_FALL) {
        k_zero   <<<NN * HD / 4 / 256, 256, 0, stream>>>(aggr);
        k_scatter<<<NE * 32 / 256,     256, 0, stream>>>(x_a, edge_ba, aggr);
    }

    k_gemm12<<<(NN + 63) / 64, 256, 0, stream>>>(aggr, x_a, xb, use_xb,
                                                 wlb, w01b, owb, bias1, bias2,
                                                 (float*)d_out);
}

// Round 11
// 225.009 us; speedup vs baseline: 12.0742x; 1.0722x over previous
//
#include <hip/hip_runtime.h>
#include <hip/hip_bf16.h>

#define NN 50000
#define NE 500000
#define HD 128
#define SCAN_B ((NN + 255) / 256)        // 196
#define PREP_B 24
#define PREPX_B 3125
#define SETUP_B (PREP_B + PREPX_B + SCAN_B)  // 3345

typedef __bf16 bf16;
typedef __attribute__((ext_vector_type(8))) __bf16 bf16x8;
typedef __attribute__((ext_vector_type(4))) float floatx4;

__device__ inline float u2f(unsigned int lo16) {
    union { unsigned int i; float f; } c; c.i = lo16 << 16; return c.f;
}

__device__ inline bf16x8 cvt8(floatx4 a, floatx4 b) {
    bf16x8 r;
#pragma unroll
    for (int j = 0; j < 4; j++) { r[j] = (bf16)a[j]; r[j + 4] = (bf16)b[j]; }
    return r;
}

__device__ inline void split8(const floatx4 f0, const floatx4 f1, bf16x8& hi, bf16x8& lo) {
#pragma unroll
    for (int j = 0; j < 4; j++) {
        float a = f0[j]; bf16 h = (bf16)a; hi[j] = h; lo[j] = (bf16)(a - (float)h);
        float b = f1[j]; bf16 g = (bf16)b; hi[j + 4] = g; lo[j + 4] = (bf16)(b - (float)g);
    }
}

__device__ inline bf16x8 zero8() {
    bf16x8 v;
#pragma unroll
    for (int j = 0; j < 8; j++) v[j] = (bf16)0.f;
    return v;
}

// ===== k_setup: weight prep (blocks 0..23) + x->bf16 (24..3148) + zero dcur (3149..3344) =====
__global__ __launch_bounds__(256) void k_setup(
    const float* __restrict__ wl, const float* __restrict__ w0, const float* __restrict__ w1,
    const float* __restrict__ bl, const float* __restrict__ b0, const float* __restrict__ b1,
    const float* __restrict__ ow, const float* __restrict__ ob,
    const float* __restrict__ x,
    bf16* __restrict__ wlb, bf16* __restrict__ w01b, bf16* __restrict__ owb,
    float* __restrict__ bias1, float* __restrict__ bias2,
    bf16* __restrict__ xb, int* __restrict__ dcur,
    int tier)
{
    const int b = blockIdx.x, tid = threadIdx.x;
    if (b < PREP_B) {
        int g = b * 256 + tid;
        int m = g >> 11, off = (g & 2047) << 3;
        if (m == 0) {
            const floatx4 a = *(const floatx4*)(wl + off);
            const floatx4 c = *(const floatx4*)(wl + off + 4);
            *(bf16x8*)(wlb + off) = cvt8(a, c);
        } else if (m == 1) {
            floatx4 a = *(const floatx4*)(w0 + off);
            floatx4 c = *(const floatx4*)(w0 + off + 4);
            const floatx4 d = *(const floatx4*)(w1 + off);
            const floatx4 e = *(const floatx4*)(w1 + off + 4);
#pragma unroll
            for (int j = 0; j < 4; j++) { a[j] += d[j]; c[j] += e[j]; }
            *(bf16x8*)(w01b + off) = cvt8(a, c);
        } else {
            const floatx4 a = *(const floatx4*)(ow + off);
            const floatx4 c = *(const floatx4*)(ow + off + 4);
            *(bf16x8*)(owb + off) = cvt8(a, c);
        }
        if (g < 128) bias1[g] = bl[g] + b0[g] + b1[g];
        else if (g < 256) bias2[g - 128] = ob[g - 128];
    } else if (b < PREP_B + PREPX_B) {
        if (tier >= 2) {
            int off = ((b - PREP_B) * 256 + tid) << 3;
            const floatx4 a = *(const floatx4*)(x + off);
            const floatx4 c = *(const floatx4*)(x + off + 4);
            *(bf16x8*)(xb + off) = cvt8(a, c);
        }
    } else {
        if (tier >= 1) {
            int i = (b - PREP_B - PREPX_B) * 256 + tid;
            if (i < NN) dcur[i] = 0;
        }
    }
}

// ================= CSR build =================
__global__ __launch_bounds__(256) void k_hist(const int* __restrict__ edge,
                                              int* __restrict__ cnt) {
    int e = blockIdx.x * 256 + threadIdx.x;
    if (e < NE) atomicAdd(&cnt[edge[e]], 1);
}

__global__ __launch_bounds__(256) void k_scan1(const int* __restrict__ cnt,
                                               int* __restrict__ excl,
                                               int* __restrict__ bsum) {
    __shared__ int s[256];
    const int t = threadIdx.x, i = blockIdx.x * 256 + t;
    int c = (i < NN) ? cnt[i] : 0;
    s[t] = c; __syncthreads();
    int v = c;
    for (int off = 1; off < 256; off <<= 1) {
        int u = (t >= off) ? s[t - off] : 0;
        __syncthreads();
        v += u; s[t] = v;
        __syncthreads();
    }
    if (i < NN) excl[i] = v - c;
    if (t == 255) bsum[blockIdx.x] = v;
}

// merged stages 2+3: each block scans the 196 block sums in LDS, applies its offset
__global__ __launch_bounds__(256) void k_scan23(int* __restrict__ offs,
                                                const int* __restrict__ bsum,
                                                int* __restrict__ cur) {
    __shared__ int s[256];
    const int t = threadIdx.x;
    int c = (t < SCAN_B) ? bsum[t] : 0;
    s[t] = c; __syncthreads();
    int v = c;
    for (int off = 1; off < 256; off <<= 1) {
        int u = (t >= off) ? s[t - off] : 0;
        __syncthreads();
        v += u; s[t] = v;
        __syncthreads();
    }
    // exclusive prefix for this block
    const int bpre = (blockIdx.x > 0) ? s[blockIdx.x - 1] : 0;
    int i = blockIdx.x * 256 + t;
    if (i < NN) {
        int o = offs[i] + bpre;
        offs[i] = o;
        cur[i] = o;
    } else if (i == NN) {
        offs[NN] = NE;
    }
}

__global__ __launch_bounds__(256) void k_fill(const int* __restrict__ edge,
                                              int* __restrict__ cur,
                                              int* __restrict__ csr_src) {
    int e = blockIdx.x * 256 + threadIdx.x;
    if (e < NE) {
        int dst = edge[e];
        int src = edge[NE + e];
        int pos = atomicAdd(&cur[dst], 1);
        csr_src[pos] = src;
    }
}

// ======== gather-aggregate over bf16 x: wave per node, lane = 2 features ========
__global__ __launch_bounds__(256) void k_aggr_b(const unsigned int* __restrict__ xb2,
                                                const int* __restrict__ offs,
                                                const int* __restrict__ csr_src,
                                                float* __restrict__ aggr) {
    int w = (blockIdx.x * 256 + threadIdx.x) >> 6;
    int lane = threadIdx.x & 63;
    if (w >= NN) return;
    int s = offs[w], e = offs[w + 1];
    float ax = 0.f, ay = 0.f;
    int d = s;
    for (; d + 3 < e; d += 4) {
        int s0 = csr_src[d], s1 = csr_src[d + 1], s2 = csr_src[d + 2], s3 = csr_src[d + 3];
        unsigned int v0 = xb2[s0 * 64 + lane];
        unsigned int v1 = xb2[s1 * 64 + lane];
        unsigned int v2 = xb2[s2 * 64 + lane];
        unsigned int v3 = xb2[s3 * 64 + lane];
        ax += u2f(v0 & 0xffff) + u2f(v1 & 0xffff) + u2f(v2 & 0xffff) + u2f(v3 & 0xffff);
        ay += u2f(v0 >> 16) + u2f(v1 >> 16) + u2f(v2 >> 16) + u2f(v3 >> 16);
    }
    for (; d < e; d++) {
        unsigned int v = xb2[csr_src[d] * 64 + lane];
        ax += u2f(v & 0xffff); ay += u2f(v >> 16);
    }
    float2 o; o.x = ax; o.y = ay;
    ((float2*)aggr)[(size_t)w * 64 + lane] = o;
}

// ======== gather-aggregate f32 (tier-1, proven) ========
__global__ __launch_bounds__(256) void k_aggr_f(const float* __restrict__ x,
                                                const int* __restrict__ offs,
                                                const int* __restrict__ csr_src,
                                                float* __restrict__ aggr) {
    int w = (blockIdx.x * 256 + threadIdx.x) >> 6;
    int lane = threadIdx.x & 63;
    if (w >= NN) return;
    int s = offs[w], e = offs[w + 1];
    const float2* xp = (const float2*)x;
    float ax = 0.f, ay = 0.f;
    int d = s;
    for (; d + 1 < e; d += 2) {
        int s0 = csr_src[d], s1 = csr_src[d + 1];
        float2 v0 = xp[(size_t)s0 * 64 + lane];
        float2 v1 = xp[(size_t)s1 * 64 + lane];
        ax += v0.x + v1.x; ay += v0.y + v1.y;
    }
    if (d < e) {
        float2 v = xp[(size_t)csr_src[d] * 64 + lane];
        ax += v.x; ay += v.y;
    }
    float2 o; o.x = ax; o.y = ay;
    ((float2*)aggr)[(size_t)w * 64 + lane] = o;
}

// ======== fallback atomic path (tier-0, proven) ========
__global__ __launch_bounds__(256) void k_zero(float* __restrict__ p) {
    int i = blockIdx.x * 256 + threadIdx.x;
    floatx4 z = {0.f, 0.f, 0.f, 0.f};
    ((floatx4*)p)[i] = z;
}

__global__ __launch_bounds__(256) void k_scatter(const float* __restrict__ x,
                                                 const int* __restrict__ edge,
                                                 float* __restrict__ aggr) {
    int tid = blockIdx.x * 256 + threadIdx.x;
    int e = tid >> 5;
    int c = (tid & 31) << 2;
    int dst = edge[e];
    int src = edge[NE + e];
    const floatx4 v = *(const floatx4*)(x + src * HD + c);
    float* ap = aggr + dst * HD + c;
    unsafeAtomicAdd(ap + 0, v[0]);
    unsafeAtomicAdd(ap + 1, v[1]);
    unsafeAtomicAdd(ap + 2, v[2]);
    unsafeAtomicAdd(ap + 3, v[3]);
}

// ======== fused GEMM1+GEMM2 with LDS overlay (~70.7 KB -> 2 blocks/CU) ========
// phase1: sA=wl, sB=w01 -> GEMM1 -> sync
// phase2: sA=ow (restage), sB=tp (h transpose overlay) -> GEMM2
__global__ __launch_bounds__(256) void k_gemm12(
    const float* __restrict__ aggr, const float* __restrict__ x, const bf16* __restrict__ xb,
    int use_xb,
    const bf16* __restrict__ wlb, const bf16* __restrict__ w01b, const bf16* __restrict__ owb,
    const float* __restrict__ bias1, const float* __restrict__ bias2,
    float* __restrict__ out)
{
    __shared__ bf16 sA[128 * 136];        // 34816 B: wl, then ow
    __shared__ bf16 sB[128 * 136];        // 34816 B: w01, then tp (33792 B)
    __shared__ float b1_s[128], b2_s[128];
    float* tp = (float*)sB;               // [4][16][132]
    const int tid = threadIdx.x;

#pragma unroll
    for (int it = 0; it < 8; it++) {
        int i = tid + it * 256;
        int r = i >> 4;
        int o = (i & 15) << 3;
        *(bf16x8*)(sA + r * 136 + o) = *(const bf16x8*)(wlb  + r * 128 + o);
        *(bf16x8*)(sB + r * 136 + o) = *(const bf16x8*)(w01b + r * 128 + o);
    }
    if (tid < 128) { b1_s[tid] = bias1[tid]; b2_s[tid] = bias2[tid]; }
    __syncthreads();

    const int lane = tid & 63;
    const int wv   = tid >> 6;
    const int ln   = lane & 15;
    const int quad = lane >> 4;
    const int row0 = blockIdx.x * 64 + wv * 16;
    const int arow = row0 + ln;
    const bool aok = arow < NN;

    floatx4 acc[8] = {};

    // ---- GEMM1 ----
#pragma unroll
    for (int kc = 0; kc < 4; kc++) {
        const int k0 = kc * 32 + quad * 8;
        bf16x8 a_hi = zero8(), a_lo = zero8(), a_x = zero8();
        if (aok) {
            const floatx4 f0 = *(const floatx4*)(aggr + arow * 128 + k0);
            const floatx4 f1 = *(const floatx4*)(aggr + arow * 128 + k0 + 4);
            split8(f0, f1, a_hi, a_lo);
            if (use_xb) {
                a_x = *(const bf16x8*)(xb + arow * 128 + k0);
            } else {
                const floatx4 g0 = *(const floatx4*)(x + arow * 128 + k0);
                const floatx4 g1 = *(const floatx4*)(x + arow * 128 + k0 + 4);
                a_x = cvt8(g0, g1);
            }
        }
#pragma unroll
        for (int nc = 0; nc < 8; nc++) {
            const bf16x8 bw  = *(const bf16x8*)(sA + (nc * 16 + ln) * 136 + k0);
            const bf16x8 bw2 = *(const bf16x8*)(sB + (nc * 16 + ln) * 136 + k0);
            acc[nc] = __builtin_amdgcn_mfma_f32_16x16x32_bf16(a_hi, bw,  acc[nc], 0, 0, 0);
            acc[nc] = __builtin_amdgcn_mfma_f32_16x16x32_bf16(a_lo, bw,  acc[nc], 0, 0, 0);
            acc[nc] = __builtin_amdgcn_mfma_f32_16x16x32_bf16(a_x,  bw2, acc[nc], 0, 0, 0);
        }
    }
    __syncthreads();   // all waves finished reading sA/sB

    // ---- overlay: restage ow into sA; park relu(h) into tp (over sB) ----
#pragma unroll
    for (int it = 0; it < 8; it++) {
        int i = tid + it * 256;
        int r = i >> 4;
        int o = (i & 15) << 3;
        *(bf16x8*)(sA + r * 136 + o) = *(const bf16x8*)(owb + r * 128 + o);
    }
#pragma unroll
    for (int nc = 0; nc < 8; nc++) {
        const int col = nc * 16 + ln;
        const float bv = b1_s[col];
#pragma unroll
        for (int r = 0; r < 4; r++) {
            float v = acc[nc][r] + bv;
            tp[wv * 2112 + (quad * 4 + r) * 132 + col] = (v > 0.f ? v : 0.f);
        }
        acc[nc][0] = acc[nc][1] = acc[nc][2] = acc[nc][3] = 0.f;
    }
    __syncthreads();

    // ---- GEMM2 ----
#pragma unroll
    for (int kc = 0; kc < 4; kc++) {
        const int k0 = kc * 32 + quad * 8;
        const floatx4 f0 = *(const floatx4*)(tp + wv * 2112 + ln * 132 + k0);
        const floatx4 f1 = *(const floatx4*)(tp + wv * 2112 + ln * 132 + k0 + 4);
        bf16x8 a_hi, a_lo;
        split8(f0, f1, a_hi, a_lo);
#pragma unroll
        for (int nc = 0; nc < 8; nc++) {
            const bf16x8 bw = *(const bf16x8*)(sA + (nc * 16 + ln) * 136 + k0);
            acc[nc] = __builtin_amdgcn_mfma_f32_16x16x32_bf16(a_hi, bw, acc[nc], 0, 0, 0);
            acc[nc] = __builtin_amdgcn_mfma_f32_16x16x32_bf16(a_lo, bw, acc[nc], 0, 0, 0);
        }
    }

#pragma unroll
    for (int nc = 0; nc < 8; nc++) {
        const int col = nc * 16 + ln;
        const float bv = b2_s[col];
#pragma unroll
        for (int r = 0; r < 4; r++) {
            const int row = row0 + quad * 4 + r;
            if (row < NN) out[row * 128 + col] = acc[nc][r] + bv;
        }
    }
}

extern "C" void kernel_launch(void* const* d_in, const int* in_sizes, int n_in,
                              void* d_out, int out_size, void* d_ws, size_t ws_size,
                              hipStream_t stream) {
    const float* x_a     = (const float*)d_in[0];
    const int*   edge_ba = (const int*)d_in[3];
    const float* c1_w0_w = (const float*)d_in[10];
    const float* c1_w0_b = (const float*)d_in[11];
    const float* c1_wl_w = (const float*)d_in[12];
    const float* c1_wl_b = (const float*)d_in[13];
    const float* c1_w1_w = (const float*)d_in[14];
    const float* c1_w1_b = (const float*)d_in[15];
    const float* out_w   = (const float*)d_in[16];
    const float* out_b   = (const float*)d_in[17];

    char* p = (char*)d_ws;
    float* aggr  = (float*)p;   p += (size_t)NN * HD * 4;   // 25.6 MB
    bf16*  wlb   = (bf16*)p;    p += 32768;
    bf16*  w01b  = (bf16*)p;    p += 32768;
    bf16*  owb   = (bf16*)p;    p += 32768;
    float* bias1 = (float*)p;   p += 512;
    float* bias2 = (float*)p;   p += 512;
    const size_t WS_FALL = (size_t)(p - (char*)d_ws);       // ~25.7 MB
    int*   offs  = (int*)p;     p += 200064;
    int*   dcur  = (int*)p;     p += 200064;
    int*   csr   = (int*)p;     p += (size_t)NE * 4;
    int*   bsum  = (int*)p;     p += 1024;
    const size_t WS_CSR = (size_t)(p - (char*)d_ws);        // ~28.1 MB
    bf16*  xb    = (bf16*)p;    p += (size_t)NN * HD * 2;   // 12.8 MB
    const size_t WS_FULL = (size_t)(p - (char*)d_ws);       // ~40.9 MB

    int tier = (ws_size >= WS_FULL) ? 2 : (ws_size >= WS_CSR) ? 1 : 0;

    k_setup<<<SETUP_B, 256, 0, stream>>>(c1_wl_w, c1_w0_w, c1_w1_w,
                                         c1_wl_b, c1_w0_b, c1_w1_b,
                                         out_w, out_b, x_a,
                                         wlb, w01b, owb, bias1, bias2,
                                         xb, dcur, tier);

    if (tier >= 1) {
        k_hist  <<<(NE + 255) / 256, 256, 0, stream>>>(edge_ba, dcur);
        k_scan1 <<<SCAN_B, 256, 0, stream>>>(dcur, offs, bsum);
        k_scan23<<<SCAN_B, 256, 0, stream>>>(offs, bsum, dcur);
        k_fill  <<<(NE + 255) / 256, 256, 0, stream>>>(edge_ba, dcur, csr);
        if (tier == 2) {
            k_aggr_b<<<(NN * 64 + 255) / 256, 256, 0, stream>>>((const unsigned int*)xb,
                                                                offs, csr, aggr);
        } else {
            k_aggr_f<<<(NN * 64 + 255) / 256, 256, 0, stream>>>(x_a, offs, csr, aggr);
        }
    } else {
        k_zero   <<<NN * HD / 4 / 256, 256, 0, stream>>>(aggr);
        k_scatter<<<NE * 32 / 256,     256, 0, stream>>>(x_a, edge_ba, aggr);
    }

    k_gemm12<<<(NN + 63) / 64, 256, 0, stream>>>(aggr, x_a, xb, (tier == 2) ? 1 : 0,
                                                 wlb, w01b, owb, bias1, bias2,
                                                 (float*)d_out);
}

// Round 12
// 200.937 us; speedup vs baseline: 13.5206x; 1.1198x over previous
//
#include <hip/hip_runtime.h>
#include <hip/hip_bf16.h>

#define NN 50000
#define NE 500000
#define HD 128
#define CAP 128
#define PREP_B 24
#define PREPX_B 3125
#define ZAGGR_B 6250
#define ZCUR_B ((NN + 255) / 256)                       // 196
#define SETUP_B (PREP_B + PREPX_B + ZAGGR_B + ZCUR_B)   // 9595

typedef __bf16 bf16;
typedef __attribute__((ext_vector_type(8))) __bf16 bf16x8;
typedef __attribute__((ext_vector_type(4))) float floatx4;

__device__ inline float u2f(unsigned int lo16) {
    union { unsigned int i; float f; } c; c.i = lo16 << 16; return c.f;
}

__device__ inline bf16x8 cvt8(floatx4 a, floatx4 b) {
    bf16x8 r;
#pragma unroll
    for (int j = 0; j < 4; j++) { r[j] = (bf16)a[j]; r[j + 4] = (bf16)b[j]; }
    return r;
}

__device__ inline void split8(const floatx4 f0, const floatx4 f1, bf16x8& hi, bf16x8& lo) {
#pragma unroll
    for (int j = 0; j < 4; j++) {
        float a = f0[j]; bf16 h = (bf16)a; hi[j] = h; lo[j] = (bf16)(a - (float)h);
        float b = f1[j]; bf16 g = (bf16)b; hi[j + 4] = g; lo[j + 4] = (bf16)(b - (float)g);
    }
}

__device__ inline bf16x8 zero8() {
    bf16x8 v;
#pragma unroll
    for (int j = 0; j < 8; j++) v[j] = (bf16)0.f;
    return v;
}

// ===== k_setup: weights->bf16 | x->bf16 | zero aggr | zero cur (disjoint block ranges) =====
__global__ __launch_bounds__(256) void k_setup(
    const float* __restrict__ wl, const float* __restrict__ w0, const float* __restrict__ w1,
    const float* __restrict__ bl, const float* __restrict__ b0, const float* __restrict__ b1,
    const float* __restrict__ ow, const float* __restrict__ ob,
    const float* __restrict__ x,
    bf16* __restrict__ wlb, bf16* __restrict__ w01b, bf16* __restrict__ owb,
    float* __restrict__ bias1, float* __restrict__ bias2,
    bf16* __restrict__ xb, float* __restrict__ aggr, int* __restrict__ cur,
    int tier)
{
    const int b = blockIdx.x, tid = threadIdx.x;
    if (b < PREP_B) {
        int g = b * 256 + tid;
        int m = g >> 11, off = (g & 2047) << 3;
        if (m == 0) {
            const floatx4 a = *(const floatx4*)(wl + off);
            const floatx4 c = *(const floatx4*)(wl + off + 4);
            *(bf16x8*)(wlb + off) = cvt8(a, c);
        } else if (m == 1) {
            floatx4 a = *(const floatx4*)(w0 + off);
            floatx4 c = *(const floatx4*)(w0 + off + 4);
            const floatx4 d = *(const floatx4*)(w1 + off);
            const floatx4 e = *(const floatx4*)(w1 + off + 4);
#pragma unroll
            for (int j = 0; j < 4; j++) { a[j] += d[j]; c[j] += e[j]; }
            *(bf16x8*)(w01b + off) = cvt8(a, c);
        } else {
            const floatx4 a = *(const floatx4*)(ow + off);
            const floatx4 c = *(const floatx4*)(ow + off + 4);
            *(bf16x8*)(owb + off) = cvt8(a, c);
        }
        if (g < 128) bias1[g] = bl[g] + b0[g] + b1[g];
        else if (g < 256) bias2[g - 128] = ob[g - 128];
    } else if (b < PREP_B + PREPX_B) {
        if (tier >= 1) {
            int off = ((b - PREP_B) * 256 + tid) << 3;
            const floatx4 a = *(const floatx4*)(x + off);
            const floatx4 c = *(const floatx4*)(x + off + 4);
            *(bf16x8*)(xb + off) = cvt8(a, c);
        }
    } else if (b < PREP_B + PREPX_B + ZAGGR_B) {
        int i = (b - PREP_B - PREPX_B) * 256 + tid;
        floatx4 z = {0.f, 0.f, 0.f, 0.f};
        ((floatx4*)aggr)[i] = z;
    } else {
        if (tier >= 1) {
            int i = (b - PREP_B - PREPX_B - ZAGGR_B) * 256 + tid;
            if (i < NN) cur[i] = 0;
        }
    }
}

// ===== bucket append: bucket[dst*CAP+pos]=src; overflow -> direct f32 atomics into aggr =====
__global__ __launch_bounds__(256) void k_fillb(const int* __restrict__ edge,
                                               const float* __restrict__ x,
                                               int* __restrict__ cur,
                                               int* __restrict__ bucket,
                                               float* __restrict__ aggr) {
    int e = blockIdx.x * 256 + threadIdx.x;
    if (e >= NE) return;
    int dst = edge[e];
    int src = edge[NE + e];
    int pos = atomicAdd(&cur[dst], 1);
    if (pos < CAP) {
        bucket[dst * CAP + pos] = src;
    } else {   // statistically never (Poisson(10) vs CAP=128) — correctness valve
        const float* xr = x + (size_t)src * HD;
        float* ar = aggr + (size_t)dst * HD;
        for (int c = 0; c < HD; c++) unsafeAtomicAdd(ar + c, xr[c]);
    }
}

// ===== gather-aggregate from bucket (bf16 x): wave per node, lane = 2 features =====
__global__ __launch_bounds__(256) void k_aggr(const unsigned int* __restrict__ xb2,
                                              const int* __restrict__ cur,
                                              const int* __restrict__ bucket,
                                              float* __restrict__ aggr) {
    int w = (blockIdx.x * 256 + threadIdx.x) >> 6;
    int lane = threadIdx.x & 63;
    if (w >= NN) return;
    int deg = cur[w];
    int n = (deg < CAP) ? deg : CAP;
    const int* bk = bucket + w * CAP;
    float ax = 0.f, ay = 0.f;
    if (deg > CAP) {   // wave-uniform; seeds with overflow atomics already in aggr
        float2 init = ((float2*)aggr)[(size_t)w * 64 + lane];
        ax = init.x; ay = init.y;
    }
    int d = 0;
    for (; d + 3 < n; d += 4) {
        int s0 = bk[d], s1 = bk[d + 1], s2 = bk[d + 2], s3 = bk[d + 3];
        unsigned int v0 = xb2[s0 * 64 + lane];
        unsigned int v1 = xb2[s1 * 64 + lane];
        unsigned int v2 = xb2[s2 * 64 + lane];
        unsigned int v3 = xb2[s3 * 64 + lane];
        ax += u2f(v0 & 0xffff) + u2f(v1 & 0xffff) + u2f(v2 & 0xffff) + u2f(v3 & 0xffff);
        ay += u2f(v0 >> 16) + u2f(v1 >> 16) + u2f(v2 >> 16) + u2f(v3 >> 16);
    }
    for (; d < n; d++) {
        unsigned int v = xb2[bk[d] * 64 + lane];
        ax += u2f(v & 0xffff); ay += u2f(v >> 16);
    }
    float2 o; o.x = ax; o.y = ay;
    ((float2*)aggr)[(size_t)w * 64 + lane] = o;
}

// ======== fallback atomic scatter (tier-0, proven; aggr pre-zeroed by setup) ========
__global__ __launch_bounds__(256) void k_scatter(const float* __restrict__ x,
                                                 const int* __restrict__ edge,
                                                 float* __restrict__ aggr) {
    int tid = blockIdx.x * 256 + threadIdx.x;
    int e = tid >> 5;
    int c = (tid & 31) << 2;
    int dst = edge[e];
    int src = edge[NE + e];
    const floatx4 v = *(const floatx4*)(x + src * HD + c);
    float* ap = aggr + dst * HD + c;
    unsafeAtomicAdd(ap + 0, v[0]);
    unsafeAtomicAdd(ap + 1, v[1]);
    unsafeAtomicAdd(ap + 2, v[2]);
    unsafeAtomicAdd(ap + 3, v[3]);
}

// ======== fused GEMM1+GEMM2 with LDS overlay (~70.7 KB -> 2 blocks/CU) ========
__global__ __launch_bounds__(256) void k_gemm12(
    const float* __restrict__ aggr, const float* __restrict__ x, const bf16* __restrict__ xb,
    int use_xb,
    const bf16* __restrict__ wlb, const bf16* __restrict__ w01b, const bf16* __restrict__ owb,
    const float* __restrict__ bias1, const float* __restrict__ bias2,
    float* __restrict__ out)
{
    __shared__ bf16 sA[128 * 136];        // wl, then ow
    __shared__ bf16 sB[128 * 136];        // w01, then tp (h transpose)
    __shared__ float b1_s[128], b2_s[128];
    float* tp = (float*)sB;               // [4][16][132]
    const int tid = threadIdx.x;

#pragma unroll
    for (int it = 0; it < 8; it++) {
        int i = tid + it * 256;
        int r = i >> 4;
        int o = (i & 15) << 3;
        *(bf16x8*)(sA + r * 136 + o) = *(const bf16x8*)(wlb  + r * 128 + o);
        *(bf16x8*)(sB + r * 136 + o) = *(const bf16x8*)(w01b + r * 128 + o);
    }
    if (tid < 128) { b1_s[tid] = bias1[tid]; b2_s[tid] = bias2[tid]; }
    __syncthreads();

    const int lane = tid & 63;
    const int wv   = tid >> 6;
    const int ln   = lane & 15;
    const int quad = lane >> 4;
    const int row0 = blockIdx.x * 64 + wv * 16;
    const int arow = row0 + ln;
    const bool aok = arow < NN;

    floatx4 acc[8] = {};

    // ---- GEMM1 ----
#pragma unroll
    for (int kc = 0; kc < 4; kc++) {
        const int k0 = kc * 32 + quad * 8;
        bf16x8 a_hi = zero8(), a_lo = zero8(), a_x = zero8();
        if (aok) {
            const floatx4 f0 = *(const floatx4*)(aggr + arow * 128 + k0);
            const floatx4 f1 = *(const floatx4*)(aggr + arow * 128 + k0 + 4);
            split8(f0, f1, a_hi, a_lo);
            if (use_xb) {
                a_x = *(const bf16x8*)(xb + arow * 128 + k0);
            } else {
                const floatx4 g0 = *(const floatx4*)(x + arow * 128 + k0);
                const floatx4 g1 = *(const floatx4*)(x + arow * 128 + k0 + 4);
                a_x = cvt8(g0, g1);
            }
        }
#pragma unroll
        for (int nc = 0; nc < 8; nc++) {
            const bf16x8 bw  = *(const bf16x8*)(sA + (nc * 16 + ln) * 136 + k0);
            const bf16x8 bw2 = *(const bf16x8*)(sB + (nc * 16 + ln) * 136 + k0);
            acc[nc] = __builtin_amdgcn_mfma_f32_16x16x32_bf16(a_hi, bw,  acc[nc], 0, 0, 0);
            acc[nc] = __builtin_amdgcn_mfma_f32_16x16x32_bf16(a_lo, bw,  acc[nc], 0, 0, 0);
            acc[nc] = __builtin_amdgcn_mfma_f32_16x16x32_bf16(a_x,  bw2, acc[nc], 0, 0, 0);
        }
    }
    __syncthreads();

    // ---- overlay: restage ow into sA; park relu(h) into tp (over sB) ----
#pragma unroll
    for (int it = 0; it < 8; it++) {
        int i = tid + it * 256;
        int r = i >> 4;
        int o = (i & 15) << 3;
        *(bf16x8*)(sA + r * 136 + o) = *(const bf16x8*)(owb + r * 128 + o);
    }
#pragma unroll
    for (int nc = 0; nc < 8; nc++) {
        const int col = nc * 16 + ln;
        const float bv = b1_s[col];
#pragma unroll
        for (int r = 0; r < 4; r++) {
            float v = acc[nc][r] + bv;
            tp[wv * 2112 + (quad * 4 + r) * 132 + col] = (v > 0.f ? v : 0.f);
        }
        acc[nc][0] = acc[nc][1] = acc[nc][2] = acc[nc][3] = 0.f;
    }
    __syncthreads();

    // ---- GEMM2 ----
#pragma unroll
    for (int kc = 0; kc < 4; kc++) {
        const int k0 = kc * 32 + quad * 8;
        const floatx4 f0 = *(const floatx4*)(tp + wv * 2112 + ln * 132 + k0);
        const floatx4 f1 = *(const floatx4*)(tp + wv * 2112 + ln * 132 + k0 + 4);
        bf16x8 a_hi, a_lo;
        split8(f0, f1, a_hi, a_lo);
#pragma unroll
        for (int nc = 0; nc < 8; nc++) {
            const bf16x8 bw = *(const bf16x8*)(sA + (nc * 16 + ln) * 136 + k0);
            acc[nc] = __builtin_amdgcn_mfma_f32_16x16x32_bf16(a_hi, bw, acc[nc], 0, 0, 0);
            acc[nc] = __builtin_amdgcn_mfma_f32_16x16x32_bf16(a_lo, bw, acc[nc], 0, 0, 0);
        }
    }

#pragma unroll
    for (int nc = 0; nc < 8; nc++) {
        const int col = nc * 16 + ln;
        const float bv = b2_s[col];
#pragma unroll
        for (int r = 0; r < 4; r++) {
            const int row = row0 + quad * 4 + r;
            if (row < NN) out[row * 128 + col] = acc[nc][r] + bv;
        }
    }
}

extern "C" void kernel_launch(void* const* d_in, const int* in_sizes, int n_in,
                              void* d_out, int out_size, void* d_ws, size_t ws_size,
                              hipStream_t stream) {
    const float* x_a     = (const float*)d_in[0];
    const int*   edge_ba = (const int*)d_in[3];
    const float* c1_w0_w = (const float*)d_in[10];
    const float* c1_w0_b = (const float*)d_in[11];
    const float* c1_wl_w = (const float*)d_in[12];
    const float* c1_wl_b = (const float*)d_in[13];
    const float* c1_w1_w = (const float*)d_in[14];
    const float* c1_w1_b = (const float*)d_in[15];
    const float* out_w   = (const float*)d_in[16];
    const float* out_b   = (const float*)d_in[17];

    char* p = (char*)d_ws;
    float* aggr  = (float*)p;   p += (size_t)NN * HD * 4;     // 25.6 MB
    bf16*  wlb   = (bf16*)p;    p += 32768;
    bf16*  w01b  = (bf16*)p;    p += 32768;
    bf16*  owb   = (bf16*)p;    p += 32768;
    float* bias1 = (float*)p;   p += 512;
    float* bias2 = (float*)p;   p += 512;
    const size_t WS_FALL = (size_t)(p - (char*)d_ws);         // ~25.7 MB
    int*   cur    = (int*)p;    p += 200704;                  // NN ints (padded)
    int*   bucket = (int*)p;    p += (size_t)NN * CAP * 4;    // 25.6 MB
    bf16*  xb     = (bf16*)p;   p += (size_t)NN * HD * 2;     // 12.8 MB
    const size_t WS_BUCKET = (size_t)(p - (char*)d_ws);       // ~64.3 MB (ws = 256 MiB)

    const int tier = (ws_size >= WS_BUCKET) ? 1 : 0;

    k_setup<<<SETUP_B, 256, 0, stream>>>(c1_wl_w, c1_w0_w, c1_w1_w,
                                         c1_wl_b, c1_w0_b, c1_w1_b,
                                         out_w, out_b, x_a,
                                         wlb, w01b, owb, bias1, bias2,
                                         xb, aggr, cur, tier);

    if (tier) {
        k_fillb<<<(NE + 255) / 256, 256, 0, stream>>>(edge_ba, x_a, cur, bucket, aggr);
        k_aggr <<<(NN * 64 + 255) / 256, 256, 0, stream>>>((const unsigned int*)xb,
                                                           cur, bucket, aggr);
    } else {
        k_scatter<<<NE * 32 / 256, 256, 0, stream>>>(x_a, edge_ba, aggr);
    }

    k_gemm12<<<(NN + 63) / 64, 256, 0, stream>>>(aggr, x_a, xb, tier,
                                                 wlb, w01b, owb, bias1, bias2,
                                                 (float*)d_out);
}

// Round 13
// 195.488 us; speedup vs baseline: 13.8975x; 1.0279x over previous
//
#include <hip/hip_runtime.h>
#include <hip/hip_bf16.h>

#define NN 50000
#define NE 500000
#define HD 128
#define CAP 128
#define PREP_B 24
#define ZCUR_B ((NN + 255) / 256)          // 196
#define ZAGGR_B 6250
#define K1_B (PREP_B + ZCUR_B + ZAGGR_B)   // 6470
#define FILLB_B ((NE + 255) / 256)         // 1954
#define XCONV_B 3125
#define K2_B (FILLB_B + XCONV_B)           // 5079

typedef __bf16 bf16;
typedef __attribute__((ext_vector_type(8))) __bf16 bf16x8;
typedef __attribute__((ext_vector_type(4))) float floatx4;

__device__ inline float u2f(unsigned int lo16) {
    union { unsigned int i; float f; } c; c.i = lo16 << 16; return c.f;
}

__device__ inline bf16x8 cvt8(floatx4 a, floatx4 b) {
    bf16x8 r;
#pragma unroll
    for (int j = 0; j < 4; j++) { r[j] = (bf16)a[j]; r[j + 4] = (bf16)b[j]; }
    return r;
}

__device__ inline void split8(const floatx4 f0, const floatx4 f1, bf16x8& hi, bf16x8& lo) {
#pragma unroll
    for (int j = 0; j < 4; j++) {
        float a = f0[j]; bf16 h = (bf16)a; hi[j] = h; lo[j] = (bf16)(a - (float)h);
        float b = f1[j]; bf16 g = (bf16)b; hi[j + 4] = g; lo[j + 4] = (bf16)(b - (float)g);
    }
}

__device__ inline bf16x8 zero8() {
    bf16x8 v;
#pragma unroll
    for (int j = 0; j < 8; j++) v[j] = (bf16)0.f;
    return v;
}

// ===== K1: weights->bf16 (24) | zero cur (196) | zero aggr (6250) =====
__global__ __launch_bounds__(256) void k_setup1(
    const float* __restrict__ wl, const float* __restrict__ w0, const float* __restrict__ w1,
    const float* __restrict__ bl, const float* __restrict__ b0, const float* __restrict__ b1,
    const float* __restrict__ ow, const float* __restrict__ ob,
    bf16* __restrict__ wlb, bf16* __restrict__ w01b, bf16* __restrict__ owb,
    float* __restrict__ bias1, float* __restrict__ bias2,
    float* __restrict__ aggr, int* __restrict__ cur, int tier)
{
    const int b = blockIdx.x, tid = threadIdx.x;
    if (b < PREP_B) {
        int g = b * 256 + tid;
        int m = g >> 11, off = (g & 2047) << 3;
        if (m == 0) {
            const floatx4 a = *(const floatx4*)(wl + off);
            const floatx4 c = *(const floatx4*)(wl + off + 4);
            *(bf16x8*)(wlb + off) = cvt8(a, c);
        } else if (m == 1) {
            floatx4 a = *(const floatx4*)(w0 + off);
            floatx4 c = *(const floatx4*)(w0 + off + 4);
            const floatx4 d = *(const floatx4*)(w1 + off);
            const floatx4 e = *(const floatx4*)(w1 + off + 4);
#pragma unroll
            for (int j = 0; j < 4; j++) { a[j] += d[j]; c[j] += e[j]; }
            *(bf16x8*)(w01b + off) = cvt8(a, c);
        } else {
            const floatx4 a = *(const floatx4*)(ow + off);
            const floatx4 c = *(const floatx4*)(ow + off + 4);
            *(bf16x8*)(owb + off) = cvt8(a, c);
        }
        if (g < 128) bias1[g] = bl[g] + b0[g] + b1[g];
        else if (g < 256) bias2[g - 128] = ob[g - 128];
    } else if (b < PREP_B + ZCUR_B) {
        if (tier >= 1) {
            int i = (b - PREP_B) * 256 + tid;
            if (i < NN) cur[i] = 0;
        }
    } else {
        int i = (b - PREP_B - ZCUR_B) * 256 + tid;
        floatx4 z = {0.f, 0.f, 0.f, 0.f};
        ((floatx4*)aggr)[i] = z;
    }
}

// ===== K2: bucket append (1954) | x->bf16 (3125) — independent, co-scheduled =====
__global__ __launch_bounds__(256) void k_setup2(
    const int* __restrict__ edge, const float* __restrict__ x,
    int* __restrict__ cur, int* __restrict__ bucket, float* __restrict__ aggr,
    bf16* __restrict__ xb)
{
    const int b = blockIdx.x, tid = threadIdx.x;
    if (b < FILLB_B) {
        int e = b * 256 + tid;
        if (e >= NE) return;
        int dst = edge[e];
        int src = edge[NE + e];
        int pos = atomicAdd(&cur[dst], 1);
        if (pos < CAP) {
            bucket[dst * CAP + pos] = src;
        } else {   // statistically never — correctness valve (aggr pre-zeroed in K1)
            const float* xr = x + (size_t)src * HD;
            float* ar = aggr + (size_t)dst * HD;
            for (int c = 0; c < HD; c++) unsafeAtomicAdd(ar + c, xr[c]);
        }
    } else {
        int off = ((b - FILLB_B) * 256 + tid) << 3;
        const floatx4 a = *(const floatx4*)(x + off);
        const floatx4 c = *(const floatx4*)(x + off + 4);
        *(bf16x8*)(xb + off) = cvt8(a, c);
    }
}

// ===== gather-aggregate: 4 nodes/wave (quad = node), lane covers 8 features (16B loads) =====
__global__ __launch_bounds__(256) void k_aggr(const bf16* __restrict__ xb,
                                              const int* __restrict__ cur,
                                              const int* __restrict__ bucket,
                                              float* __restrict__ aggr) {
    const int gw   = (blockIdx.x * 256 + threadIdx.x) >> 6;   // wave id
    const int lane = threadIdx.x & 63;
    const int quad = lane >> 4;
    const int ln   = lane & 15;
    const int node = gw * 4 + quad;                            // 50000/4 = 12500 waves exactly
    const bool ok  = node < NN;

    float acc[8] = {0.f, 0.f, 0.f, 0.f, 0.f, 0.f, 0.f, 0.f};
    int deg = 0, n = 0;
    const int* bk = bucket;
    if (ok) {
        deg = cur[node];
        n = (deg < CAP) ? deg : CAP;
        bk = bucket + node * CAP;
        if (deg > CAP) {   // seed with overflow atomics already in aggr
            const floatx4 s0 = *(const floatx4*)(aggr + node * HD + ln * 8);
            const floatx4 s1 = *(const floatx4*)(aggr + node * HD + ln * 8 + 4);
#pragma unroll
            for (int j = 0; j < 4; j++) { acc[j] = s0[j]; acc[4 + j] = s1[j]; }
        }
    }

    int t = 0;
    for (; t + 3 < n; t += 4) {       // 4 outstanding 16B loads per lane
        int s0 = bk[t], s1 = bk[t + 1], s2 = bk[t + 2], s3 = bk[t + 3];
        const uint4 v0 = *(const uint4*)(xb + s0 * HD + ln * 8);
        const uint4 v1 = *(const uint4*)(xb + s1 * HD + ln * 8);
        const uint4 v2 = *(const uint4*)(xb + s2 * HD + ln * 8);
        const uint4 v3 = *(const uint4*)(xb + s3 * HD + ln * 8);
        const unsigned int u0[4] = {v0.x, v0.y, v0.z, v0.w};
        const unsigned int u1[4] = {v1.x, v1.y, v1.z, v1.w};
        const unsigned int u2[4] = {v2.x, v2.y, v2.z, v2.w};
        const unsigned int u3[4] = {v3.x, v3.y, v3.z, v3.w};
#pragma unroll
        for (int j = 0; j < 4; j++) {
            acc[2 * j]     += u2f(u0[j] & 0xffff) + u2f(u1[j] & 0xffff)
                            + u2f(u2[j] & 0xffff) + u2f(u3[j] & 0xffff);
            acc[2 * j + 1] += u2f(u0[j] >> 16) + u2f(u1[j] >> 16)
                            + u2f(u2[j] >> 16) + u2f(u3[j] >> 16);
        }
    }
    for (; t < n; t++) {
        const uint4 v = *(const uint4*)(xb + bk[t] * HD + ln * 8);
        const unsigned int u[4] = {v.x, v.y, v.z, v.w};
#pragma unroll
        for (int j = 0; j < 4; j++) {
            acc[2 * j]     += u2f(u[j] & 0xffff);
            acc[2 * j + 1] += u2f(u[j] >> 16);
        }
    }

    if (ok) {
        floatx4 o0, o1;
#pragma unroll
        for (int j = 0; j < 4; j++) { o0[j] = acc[j]; o1[j] = acc[4 + j]; }
        *(floatx4*)(aggr + node * HD + ln * 8) = o0;
        *(floatx4*)(aggr + node * HD + ln * 8 + 4) = o1;
    }
}

// ======== fallback atomic scatter (tier-0, proven; aggr pre-zeroed by K1) ========
__global__ __launch_bounds__(256) void k_scatter(const float* __restrict__ x,
                                                 const int* __restrict__ edge,
                                                 float* __restrict__ aggr) {
    int tid = blockIdx.x * 256 + threadIdx.x;
    int e = tid >> 5;
    int c = (tid & 31) << 2;
    int dst = edge[e];
    int src = edge[NE + e];
    const floatx4 v = *(const floatx4*)(x + src * HD + c);
    float* ap = aggr + dst * HD + c;
    unsafeAtomicAdd(ap + 0, v[0]);
    unsafeAtomicAdd(ap + 1, v[1]);
    unsafeAtomicAdd(ap + 2, v[2]);
    unsafeAtomicAdd(ap + 3, v[3]);
}

// ======== fused GEMM1+GEMM2 with LDS overlay (~70.7 KB -> 2 blocks/CU) ========
__global__ __launch_bounds__(256) void k_gemm12(
    const float* __restrict__ aggr, const float* __restrict__ x, const bf16* __restrict__ xb,
    int use_xb,
    const bf16* __restrict__ wlb, const bf16* __restrict__ w01b, const bf16* __restrict__ owb,
    const float* __restrict__ bias1, const float* __restrict__ bias2,
    float* __restrict__ out)
{
    __shared__ bf16 sA[128 * 136];        // wl, then ow
    __shared__ bf16 sB[128 * 136];        // w01, then tp (h transpose)
    __shared__ float b1_s[128], b2_s[128];
    float* tp = (float*)sB;               // [4][16][132]
    const int tid = threadIdx.x;

#pragma unroll
    for (int it = 0; it < 8; it++) {
        int i = tid + it * 256;
        int r = i >> 4;
        int o = (i & 15) << 3;
        *(bf16x8*)(sA + r * 136 + o) = *(const bf16x8*)(wlb  + r * 128 + o);
        *(bf16x8*)(sB + r * 136 + o) = *(const bf16x8*)(w01b + r * 128 + o);
    }
    if (tid < 128) { b1_s[tid] = bias1[tid]; b2_s[tid] = bias2[tid]; }
    __syncthreads();

    const int lane = tid & 63;
    const int wv   = tid >> 6;
    const int ln   = lane & 15;
    const int quad = lane >> 4;
    const int row0 = blockIdx.x * 64 + wv * 16;
    const int arow = row0 + ln;
    const bool aok = arow < NN;

    floatx4 acc[8] = {};

    // ---- GEMM1 ----
#pragma unroll
    for (int kc = 0; kc < 4; kc++) {
        const int k0 = kc * 32 + quad * 8;
        bf16x8 a_hi = zero8(), a_lo = zero8(), a_x = zero8();
        if (aok) {
            const floatx4 f0 = *(const floatx4*)(aggr + arow * 128 + k0);
            const floatx4 f1 = *(const floatx4*)(aggr + arow * 128 + k0 + 4);
            split8(f0, f1, a_hi, a_lo);
            if (use_xb) {
                a_x = *(const bf16x8*)(xb + arow * 128 + k0);
            } else {
                const floatx4 g0 = *(const floatx4*)(x + arow * 128 + k0);
                const floatx4 g1 = *(const floatx4*)(x + arow * 128 + k0 + 4);
                a_x = cvt8(g0, g1);
            }
        }
#pragma unroll
        for (int nc = 0; nc < 8; nc++) {
            const bf16x8 bw  = *(const bf16x8*)(sA + (nc * 16 + ln) * 136 + k0);
            const bf16x8 bw2 = *(const bf16x8*)(sB + (nc * 16 + ln) * 136 + k0);
            acc[nc] = __builtin_amdgcn_mfma_f32_16x16x32_bf16(a_hi, bw,  acc[nc], 0, 0, 0);
            acc[nc] = __builtin_amdgcn_mfma_f32_16x16x32_bf16(a_lo, bw,  acc[nc], 0, 0, 0);
            acc[nc] = __builtin_amdgcn_mfma_f32_16x16x32_bf16(a_x,  bw2, acc[nc], 0, 0, 0);
        }
    }
    __syncthreads();

    // ---- overlay: restage ow into sA; park relu(h) into tp (over sB) ----
#pragma unroll
    for (int it = 0; it < 8; it++) {
        int i = tid + it * 256;
        int r = i >> 4;
        int o = (i & 15) << 3;
        *(bf16x8*)(sA + r * 136 + o) = *(const bf16x8*)(owb + r * 128 + o);
    }
#pragma unroll
    for (int nc = 0; nc < 8; nc++) {
        const int col = nc * 16 + ln;
        const float bv = b1_s[col];
#pragma unroll
        for (int r = 0; r < 4; r++) {
            float v = acc[nc][r] + bv;
            tp[wv * 2112 + (quad * 4 + r) * 132 + col] = (v > 0.f ? v : 0.f);
        }
        acc[nc][0] = acc[nc][1] = acc[nc][2] = acc[nc][3] = 0.f;
    }
    __syncthreads();

    // ---- GEMM2 ----
#pragma unroll
    for (int kc = 0; kc < 4; kc++) {
        const int k0 = kc * 32 + quad * 8;
        const floatx4 f0 = *(const floatx4*)(tp + wv * 2112 + ln * 132 + k0);
        const floatx4 f1 = *(const floatx4*)(tp + wv * 2112 + ln * 132 + k0 + 4);
        bf16x8 a_hi, a_lo;
        split8(f0, f1, a_hi, a_lo);
#pragma unroll
        for (int nc = 0; nc < 8; nc++) {
            const bf16x8 bw = *(const bf16x8*)(sA + (nc * 16 + ln) * 136 + k0);
            acc[nc] = __builtin_amdgcn_mfma_f32_16x16x32_bf16(a_hi, bw, acc[nc], 0, 0, 0);
            acc[nc] = __builtin_amdgcn_mfma_f32_16x16x32_bf16(a_lo, bw, acc[nc], 0, 0, 0);
        }
    }

#pragma unroll
    for (int nc = 0; nc < 8; nc++) {
        const int col = nc * 16 + ln;
        const float bv = b2_s[col];
#pragma unroll
        for (int r = 0; r < 4; r++) {
            const int row = row0 + quad * 4 + r;
            if (row < NN) out[row * 128 + col] = acc[nc][r] + bv;
        }
    }
}

extern "C" void kernel_launch(void* const* d_in, const int* in_sizes, int n_in,
                              void* d_out, int out_size, void* d_ws, size_t ws_size,
                              hipStream_t stream) {
    const float* x_a     = (const float*)d_in[0];
    const int*   edge_ba = (const int*)d_in[3];
    const float* c1_w0_w = (const float*)d_in[10];
    const float* c1_w0_b = (const float*)d_in[11];
    const float* c1_wl_w = (const float*)d_in[12];
    const float* c1_wl_b = (const float*)d_in[13];
    const float* c1_w1_w = (const float*)d_in[14];
    const float* c1_w1_b = (const float*)d_in[15];
    const float* out_w   = (const float*)d_in[16];
    const float* out_b   = (const float*)d_in[17];

    char* p = (char*)d_ws;
    float* aggr  = (float*)p;   p += (size_t)NN * HD * 4;     // 25.6 MB
    bf16*  wlb   = (bf16*)p;    p += 32768;
    bf16*  w01b  = (bf16*)p;    p += 32768;
    bf16*  owb   = (bf16*)p;    p += 32768;
    float* bias1 = (float*)p;   p += 512;
    float* bias2 = (float*)p;   p += 512;
    const size_t WS_FALL = (size_t)(p - (char*)d_ws);         // ~25.7 MB
    int*   cur    = (int*)p;    p += 200704;                  // NN ints (padded)
    int*   bucket = (int*)p;    p += (size_t)NN * CAP * 4;    // 25.6 MB
    bf16*  xb     = (bf16*)p;   p += (size_t)NN * HD * 2;     // 12.8 MB
    const size_t WS_BUCKET = (size_t)(p - (char*)d_ws);       // ~64.3 MB (ws = 256 MiB)

    const int tier = (ws_size >= WS_BUCKET) ? 1 : 0;

    k_setup1<<<K1_B, 256, 0, stream>>>(c1_wl_w, c1_w0_w, c1_w1_w,
                                       c1_wl_b, c1_w0_b, c1_w1_b,
                                       out_w, out_b,
                                       wlb, w01b, owb, bias1, bias2,
                                       aggr, cur, tier);

    if (tier) {
        k_setup2<<<K2_B, 256, 0, stream>>>(edge_ba, x_a, cur, bucket, aggr, xb);
        k_aggr  <<<3125, 256, 0, stream>>>(xb, cur, bucket, aggr);
    } else {
        k_scatter<<<NE * 32 / 256, 256, 0, stream>>>(x_a, edge_ba, aggr);
    }

    k_gemm12<<<(NN + 63) / 64, 256, 0, stream>>>(aggr, x_a, xb, tier,
                                                 wlb, w01b, owb, bias1, bias2,
                                                 (float*)d_out);
}